// Round 10
// baseline (286.541 us; speedup 1.0000x reference)
//
#include <hip/hip_runtime.h>

#define BB 8
#define TT 2048
#define CC 1024
#define WKV_L 32
#define WKV_NCH (TT / WKV_L)   // 64 chunks
#define WKV_LOG_NCH 6

typedef __bf16 bf16x8_t __attribute__((ext_vector_type(8)));
typedef float f32x4_t __attribute__((ext_vector_type(4)));
typedef unsigned short ushort8_t __attribute__((ext_vector_type(8)));

__device__ __forceinline__ unsigned short f2bf(float f) {
  unsigned u = __float_as_uint(f);
  u += 0x7fffu + ((u >> 16) & 1u);   // round-to-nearest-even
  return (unsigned short)(u >> 16);
}
__device__ __forceinline__ float bf2f(unsigned short s) {
  return __uint_as_float(((unsigned)s) << 16);
}

#define GLOAD16(gp, lp)                                                        \
  __builtin_amdgcn_global_load_lds(                                            \
      (const __attribute__((address_space(1))) void*)(gp),                     \
      (__attribute__((address_space(3))) void*)(lp), 16, 0, 0)

// ---- fused mix (block-specialized per output) + weight casts ------------
// Blocks [0,3072): which = bid%3 (xk/xv/xr), slab = bid/3. One contiguous
// write stream per block; 3 blocks of a slab read the same x region (L2-hot).
// Blocks [3072,3136): the 4 weight casts.
#define MIX_BLOCKS 3072
#define SLAB8 2048            // ushort8 groups per slab (16384 elems)

__global__ __launch_bounds__(256) void mix_castw_kernel(
    const float* __restrict__ x, const float* __restrict__ tmk,
    const float* __restrict__ tmv, const float* __restrict__ tmr,
    unsigned short* __restrict__ xk, unsigned short* __restrict__ xv,
    unsigned short* __restrict__ xr,
    const float* __restrict__ w0, const float* __restrict__ w1,
    const float* __restrict__ w2, const float* __restrict__ w3,
    unsigned short* __restrict__ o0, unsigned short* __restrict__ o1,
    unsigned short* __restrict__ o2, unsigned short* __restrict__ o3) {
  const int bid = blockIdx.x;
  const int tid = threadIdx.x;
  if (bid < MIX_BLOCKS) {
    const int which = bid % 3;
    const int slab = bid / 3;
    const float* tm = which == 0 ? tmk : which == 1 ? tmv : tmr;
    unsigned short* out = which == 0 ? xk : which == 1 ? xv : xr;
#pragma unroll 2
    for (int it = 0; it < SLAB8 / 256; ++it) {
      size_t idx8 = (size_t)slab * SLAB8 + it * 256 + tid;
      size_t e = idx8 * 8;
      int c = (int)(e & (CC - 1));
      int t = (int)((e >> 10) & (TT - 1));
      float4 xa = *(const float4*)(x + e);
      float4 xb = *(const float4*)(x + e + 4);
      float4 pa = make_float4(0.f, 0.f, 0.f, 0.f), pb = pa;
      if (t > 0) {
        pa = *(const float4*)(x + e - CC);
        pb = *(const float4*)(x + e - CC + 4);
      }
      float4 ma = *(const float4*)(tm + c);
      float4 mb = *(const float4*)(tm + c + 4);
      ushort8_t o;
      o[0] = f2bf(xa.x * ma.x + pa.x * (1.f - ma.x));
      o[1] = f2bf(xa.y * ma.y + pa.y * (1.f - ma.y));
      o[2] = f2bf(xa.z * ma.z + pa.z * (1.f - ma.z));
      o[3] = f2bf(xa.w * ma.w + pa.w * (1.f - ma.w));
      o[4] = f2bf(xb.x * mb.x + pb.x * (1.f - mb.x));
      o[5] = f2bf(xb.y * mb.y + pb.y * (1.f - mb.y));
      o[6] = f2bf(xb.z * mb.z + pb.z * (1.f - mb.z));
      o[7] = f2bf(xb.w * mb.w + pb.w * (1.f - mb.w));
      *(ushort8_t*)(out + e) = o;
    }
  } else {
    const int n4 = CC * CC / 4;   // per weight
    for (int i = (bid - MIX_BLOCKS) * 256 + tid; i < 4 * n4;
         i += (gridDim.x - MIX_BLOCKS) * 256) {
      int sel = i / n4;
      int j = i - sel * n4;
      const float* w = sel == 0 ? w0 : sel == 1 ? w1 : sel == 2 ? w2 : w3;
      unsigned short* o = sel == 0 ? o0 : sel == 1 ? o1 : sel == 2 ? o2 : o3;
      float4 v = ((const float4*)w)[j];
      ushort4 u;
      u.x = f2bf(v.x); u.y = f2bf(v.y); u.z = f2bf(v.z); u.w = f2bf(v.w);
      ((ushort4*)o)[j] = u;
    }
  }
}

// ---- 256x256 8-phase GEMM (T2+T3+T4+T5), unchanged from R9 --------------
#define NT8 (CC / 64)   // 16 K-tiles

template <typename EPI>
__device__ __forceinline__ void gemm8_body(unsigned short* lds8,
                                           const unsigned short* __restrict__ A,
                                           const unsigned short* __restrict__ Bm,
                                           int tm, int tn, EPI epi) {
  const int tid = threadIdx.x;
  const int lane = tid & 63;
  const int wid = tid >> 6;
  const int wr = wid >> 2;   // 0..1
  const int wc = wid & 3;    // 0..3
  const int fr = lane & 15;
  const int fk = lane >> 4;  // 0..3

  const int srow = tid >> 3;                          // 0..63
  const int gcol = (((tid & 7) ^ (srow & 7)) << 3);   // pre-swizzled global col
  const unsigned short* Ag = A + (size_t)(tm * 256 + srow) * CC + gcol;
  const unsigned short* Bg = Bm + (size_t)(tn * 256 + srow) * CC + gcol;
  const int ldst = tid << 3;                          // linear LDS dest (elems)

  const int rowA = wr * 16 + fr;
  const int rowB = wc * 16 + fr;
  const int sx0 = ((fk ^ (fr & 7)) << 3);             // read-side un-swizzle, kk=0
  const int sx1 = (((4 + fk) ^ (fr & 7)) << 3);       // kk=1

  bf16x8_t aF[4][2];      // current mh half: [i][kk]
  bf16x8_t bF[2][2][2];   // both nh halves:  [nh][j][kk]
  f32x4_t acc[8][4] = {};

#define STG_A(T, H)                                                            \
  {                                                                            \
    const unsigned short* g_ = Ag + (size_t)((H) * 128) * CC + (T) * 64;       \
    unsigned short* l_ = &lds8[(((T) & 1) << 14) + (H) * 8192 + ldst];         \
    GLOAD16(g_, l_);                                                           \
    GLOAD16(g_ + (size_t)64 * CC, l_ + 4096);                                  \
  }
#define STG_B(T, H)                                                            \
  {                                                                            \
    const unsigned short* g_ = Bg + (size_t)((H) * 128) * CC + (T) * 64;       \
    unsigned short* l_ = &lds8[32768 + (((T) & 1) << 14) + (H) * 8192 + ldst]; \
    GLOAD16(g_, l_);                                                           \
    GLOAD16(g_ + (size_t)64 * CC, l_ + 4096);                                  \
  }
#define LOADA(MH)                                                              \
  _Pragma("unroll") for (int i_ = 0; i_ < 4; ++i_) {                           \
    aF[i_][0] = *(const bf16x8_t*)&lds8[ab + ((MH) * 4 + i_) * 2048 + sx0];    \
    aF[i_][1] = *(const bf16x8_t*)&lds8[ab + ((MH) * 4 + i_) * 2048 + sx1];    \
  }
#define LOADB(NH)                                                              \
  _Pragma("unroll") for (int j_ = 0; j_ < 2; ++j_) {                           \
    bF[NH][j_][0] = *(const bf16x8_t*)&lds8[bb + ((NH) * 2 + j_) * 4096 + sx0];\
    bF[NH][j_][1] = *(const bf16x8_t*)&lds8[bb + ((NH) * 2 + j_) * 4096 + sx1];\
  }
#define MFMAQ(MH, NH)                                                          \
  _Pragma("unroll") for (int i_ = 0; i_ < 4; ++i_)                             \
  _Pragma("unroll") for (int j_ = 0; j_ < 2; ++j_) {                           \
    acc[(MH) * 4 + i_][(NH) * 2 + j_] = __builtin_amdgcn_mfma_f32_16x16x32_bf16( \
        aF[i_][0], bF[NH][j_][0], acc[(MH) * 4 + i_][(NH) * 2 + j_], 0, 0, 0); \
    acc[(MH) * 4 + i_][(NH) * 2 + j_] = __builtin_amdgcn_mfma_f32_16x16x32_bf16( \
        aF[i_][1], bF[NH][j_][1], acc[(MH) * 4 + i_][(NH) * 2 + j_], 0, 0, 0); \
  }

  STG_A(0, 0) STG_B(0, 0) STG_A(0, 1) STG_B(0, 1)
  STG_A(1, 0) STG_B(1, 0) STG_A(1, 1)
  asm volatile("s_waitcnt vmcnt(10)" ::: "memory");
  __builtin_amdgcn_s_barrier();

#pragma unroll
  for (int t = 0; t < NT8; ++t) {
    const int ab = ((t & 1) << 14) + rowA * 64;
    const int bb = 32768 + ((t & 1) << 14) + rowB * 64;
    LOADA(0) LOADB(0)
    if (t + 1 < NT8) { STG_B(t + 1, 1) }
    asm volatile("s_waitcnt vmcnt(8)" ::: "memory");
    __builtin_amdgcn_s_barrier();
    __builtin_amdgcn_s_setprio(1);
    MFMAQ(0, 0)
    __builtin_amdgcn_s_setprio(0);
    __builtin_amdgcn_s_barrier();
    LOADB(1)
    if (t + 2 < NT8) { STG_A(t + 2, 0) }
    __builtin_amdgcn_s_barrier();
    __builtin_amdgcn_s_setprio(1);
    MFMAQ(0, 1)
    __builtin_amdgcn_s_setprio(0);
    __builtin_amdgcn_s_barrier();
    LOADA(1)
    if (t + 2 < NT8) { STG_B(t + 2, 0) }
    __builtin_amdgcn_s_barrier();
    __builtin_amdgcn_s_setprio(1);
    MFMAQ(1, 0)
    __builtin_amdgcn_s_setprio(0);
    __builtin_amdgcn_s_barrier();
    if (t + 2 < NT8) { STG_A(t + 2, 1) }
    asm volatile("s_waitcnt vmcnt(10)" ::: "memory");
    __builtin_amdgcn_s_barrier();
    __builtin_amdgcn_s_setprio(1);
    MFMAQ(1, 1)
    __builtin_amdgcn_s_setprio(0);
    __builtin_amdgcn_s_barrier();
  }

#pragma unroll
  for (int im = 0; im < 8; ++im)
#pragma unroll
    for (int jn = 0; jn < 4; ++jn)
#pragma unroll
      for (int rg = 0; rg < 4; ++rg)
        epi((size_t)(tm * 256 + wr * 16 + im * 32 + (fk << 2) + rg) * CC +
                (size_t)(tn * 256 + wc * 16 + jn * 64 + fr),
            acc[im][jn][rg]);
#undef STG_A
#undef STG_B
#undef LOADA
#undef LOADB
#undef MFMAQ
}

// merged k/v/r projection: 768 blocks, XCD-swizzled, all outputs bf16
__global__ __launch_bounds__(512, 2) void gemm8_kvr(
    const unsigned short* __restrict__ xk, const unsigned short* __restrict__ xv,
    const unsigned short* __restrict__ xr, const unsigned short* __restrict__ Wk,
    const unsigned short* __restrict__ Wv, const unsigned short* __restrict__ Wr,
    unsigned short* __restrict__ kout, unsigned short* __restrict__ vout,
    unsigned short* __restrict__ rout) {
  __shared__ unsigned short lds8[65536];   // 128 KB
  int orig = blockIdx.x;
  int wg = (orig & 7) * 96 + (orig >> 3);
  int which = wg >> 8;        // 256 tiles per matrix
  int rr = wg & 255;
  int tm = rr >> 2;           // tn-fast within XCD chunk
  int tn = rr & 3;
  const unsigned short* A = which == 0 ? xk : which == 1 ? xv : xr;
  const unsigned short* Bm = which == 0 ? Wk : which == 1 ? Wv : Wr;
  unsigned short* o = which == 0 ? kout : which == 1 ? vout : rout;
  gemm8_body(lds8, A, Bm, tm, tn,
             [&](size_t off, float val) { o[off] = f2bf(val); });
}

// single GEMM (256 blocks, XCD-swizzled), fp32 out (final projection)
__global__ __launch_bounds__(512, 2) void gemm8_one(const unsigned short* __restrict__ A,
                         const unsigned short* __restrict__ Bm,
                         float* __restrict__ Cm) {
  __shared__ unsigned short lds8[65536];   // 128 KB
  int orig = blockIdx.x;
  int wg = (orig & 7) * 32 + (orig >> 3);
  int tm = wg >> 2;
  int tn = wg & 3;
  gemm8_body(lds8, A, Bm, tm, tn,
             [&](size_t off, float val) { Cm[off] = val; });
}

// ---- Chunk-parallel WKV scan, anchor-decay, 2 ch/thread, load pipeline ---
__global__ __launch_bounds__(256) void wkv_phase1(const unsigned short* __restrict__ k,
                           const unsigned short* __restrict__ v,
                           const float* __restrict__ wdec,
                           float* __restrict__ Sa, float* __restrict__ Sb,
                           float* __restrict__ Sp) {
  int idx = blockIdx.x * blockDim.x + threadIdx.x;  // (b*NCH + j)*(CC/2) + c2
  int c = (idx & (CC / 2 - 1)) << 1;
  int bj = idx >> 9;
  int j = bj & (WKV_NCH - 1);
  int b = bj >> WKV_LOG_NCH;
  float w0 = -__expf(wdec[c]), w1 = -__expf(wdec[c + 1]);
  size_t off = ((size_t)b * TT + (size_t)j * WKV_L) * CC + c;
  float aa0 = 0.f, bb0 = 0.f, pp0 = -1e38f;
  float aa1 = 0.f, bb1 = 0.f, pp1 = -1e38f;
  ushort2 kk = *(const ushort2*)(k + off);
  ushort2 vv = *(const ushort2*)(v + off);
  for (int t = 0; t < WKV_L; ++t) {
    size_t noff = off + ((t + 1 < WKV_L) ? CC : 0);
    ushort2 nk = *(const ushort2*)(k + noff);
    ushort2 nv = *(const ushort2*)(v + noff);
    float k0 = bf2f(kk.x), k1 = bf2f(kk.y);
    float v0 = bf2f(vv.x), v1 = bf2f(vv.y);
    pp0 += w0; pp1 += w1;
    float d0 = k0 - pp0, d1 = k1 - pp1;
    if (d0 > 8.f) { float s = __expf(-d0); aa0 *= s; bb0 *= s; pp0 = k0; d0 = 0.f; }
    if (d1 > 8.f) { float s = __expf(-d1); aa1 *= s; bb1 *= s; pp1 = k1; d1 = 0.f; }
    float E0 = __expf(d0), E1 = __expf(d1);
    aa0 = fmaf(E0, v0, aa0); bb0 += E0;
    aa1 = fmaf(E1, v1, aa1); bb1 += E1;
    kk = nk; vv = nv; off = noff;
  }
  size_t s = (size_t)bj * CC + c;
  *(float2*)(Sa + s) = make_float2(aa0, aa1);
  *(float2*)(Sb + s) = make_float2(bb0, bb1);
  *(float2*)(Sp + s) = make_float2(pp0, pp1);
}

// serial scan over chunk summaries -> incoming state per chunk
__global__ __launch_bounds__(256) void wkv_phase2(const float* __restrict__ wdec,
                           const float* __restrict__ Sa, const float* __restrict__ Sb,
                           const float* __restrict__ Sp,
                           float* __restrict__ Ia, float* __restrict__ Ib,
                           float* __restrict__ Ip) {
  int idx = blockIdx.x * blockDim.x + threadIdx.x;  // b*CC + c
  if (idx >= BB * CC) return;
  int c = idx & (CC - 1);
  int b = idx >> 10;
  float wL = -__expf(wdec[c]) * (float)WKV_L;
  float aa = 0.f, bb = 0.f, pp = -1e38f;
  for (int j = 0; j < WKV_NCH; ++j) {
    size_t s = (size_t)(b * WKV_NCH + j) * CC + c;
    Ia[s] = aa; Ib[s] = bb; Ip[s] = pp;
    float pd = pp + wL;
    float ps = Sp[s];
    float q = fmaxf(pd, ps);
    float e1 = __expf(pd - q);
    float e2 = __expf(ps - q);
    aa = fmaf(e1, aa, e2 * Sa[s]);
    bb = fmaf(e1, bb, e2 * Sb[s]);
    pp = q;
  }
}

// phase3: anchor-decay replay + fused sigmoid(r)*y, 2 ch/thread, in-place,
// with t+1 load prefetch.
__global__ __launch_bounds__(256) void wkv_phase3(const unsigned short* __restrict__ k,
                           const unsigned short* __restrict__ v,
                           const unsigned short* r,
                           const float* __restrict__ wdec,
                           const float* __restrict__ u,
                           const float* __restrict__ Ia, const float* __restrict__ Ib,
                           const float* __restrict__ Ip,
                           unsigned short* out) {
  int idx = blockIdx.x * blockDim.x + threadIdx.x;
  int c = (idx & (CC / 2 - 1)) << 1;
  int bj = idx >> 9;
  int j = bj & (WKV_NCH - 1);
  int b = bj >> WKV_LOG_NCH;
  float w0 = -__expf(wdec[c]), w1 = -__expf(wdec[c + 1]);
  float u0 = u[c], u1 = u[c + 1];
  size_t st = (size_t)bj * CC + c;
  float2 a2 = *(const float2*)(Ia + st);
  float2 b2 = *(const float2*)(Ib + st);
  float2 p2 = *(const float2*)(Ip + st);
  float aa0 = a2.x, bb0 = b2.x, pp0 = p2.x;
  float aa1 = a2.y, bb1 = b2.y, pp1 = p2.y;
  size_t off = ((size_t)b * TT + (size_t)j * WKV_L) * CC + c;
  ushort2 kk = *(const ushort2*)(k + off);
  ushort2 vv = *(const ushort2*)(v + off);
  ushort2 rr2 = *(const ushort2*)(r + off);
  for (int t = 0; t < WKV_L; ++t) {
    size_t noff = off + ((t + 1 < WKV_L) ? CC : 0);
    ushort2 nk = *(const ushort2*)(k + noff);
    ushort2 nv = *(const ushort2*)(v + noff);
    ushort2 nr = *(const ushort2*)(r + noff);
    float k0 = bf2f(kk.x), k1 = bf2f(kk.y);
    float v0 = bf2f(vv.x), v1 = bf2f(vv.y);
    // y from pre-decay state
    float dy0 = fminf(u0 + k0 - pp0, 60.f);
    float dy1 = fminf(u1 + k1 - pp1, 60.f);
    float Eu0 = __expf(dy0), Eu1 = __expf(dy1);
    float y0 = fmaf(Eu0, v0, aa0) / (bb0 + Eu0);
    float y1 = fmaf(Eu1, v1, aa1) / (bb1 + Eu1);
    float sr0 = 1.f / (1.f + __expf(-bf2f(rr2.x)));
    float sr1 = 1.f / (1.f + __expf(-bf2f(rr2.y)));
    ushort2 o;
    o.x = f2bf(sr0 * y0);
    o.y = f2bf(sr1 * y1);
    *(ushort2*)(out + off) = o;
    // decay + rare renorm + accumulate
    pp0 += w0; pp1 += w1;
    float d0 = k0 - pp0, d1 = k1 - pp1;
    if (d0 > 8.f) { float s = __expf(-d0); aa0 *= s; bb0 *= s; pp0 = k0; d0 = 0.f; }
    if (d1 > 8.f) { float s = __expf(-d1); aa1 *= s; bb1 *= s; pp1 = k1; d1 = 0.f; }
    float E0 = __expf(d0), E1 = __expf(d1);
    aa0 = fmaf(E0, v0, aa0); bb0 += E0;
    aa1 = fmaf(E1, v1, aa1); bb1 += E1;
    kk = nk; vv = nv; rr2 = nr; off = noff;
  }
}

extern "C" void kernel_launch(void* const* d_in, const int* in_sizes, int n_in,
                              void* d_out, int out_size, void* d_ws, size_t ws_size,
                              hipStream_t stream) {
  const float* x    = (const float*)d_in[0];
  const float* tdec = (const float*)d_in[1];
  const float* tfir = (const float*)d_in[2];
  const float* tmk  = (const float*)d_in[3];
  const float* tmv  = (const float*)d_in[4];
  const float* tmr  = (const float*)d_in[5];
  const float* Wk   = (const float*)d_in[6];
  const float* Wv   = (const float*)d_in[7];
  const float* Wr   = (const float*)d_in[8];
  const float* Wo   = (const float*)d_in[9];

  const size_t M = (size_t)BB * TT;     // 16384
  const size_t mixbytes = M * CC * 2;   // 33.5 MB
  const size_t wbytes = (size_t)CC * CC * 2;
  const size_t nstate = (size_t)BB * WKV_NCH * CC;   // 512K

  // Layout (~209 MB peak, proven fit):
  char* ws = (char*)d_ws;
  unsigned short* xkb = (unsigned short*)ws;  ws += mixbytes;
  unsigned short* xvb = (unsigned short*)ws;  ws += mixbytes;
  unsigned short* xrb = (unsigned short*)ws;  ws += mixbytes;
  unsigned short* Wkb = (unsigned short*)ws; ws += wbytes;
  unsigned short* Wvb = (unsigned short*)ws; ws += wbytes;
  unsigned short* Wrb = (unsigned short*)ws; ws += wbytes;
  unsigned short* Wob = (unsigned short*)ws; ws += wbytes;
  unsigned short* kbuf = (unsigned short*)ws; ws += mixbytes;
  unsigned short* vbuf = (unsigned short*)ws; ws += mixbytes;
  unsigned short* rbuf = (unsigned short*)ws; ws += mixbytes;
  // states overlay the dead xk/xv regions (12.6 MB < 67 MB)
  char* so = (char*)xkb;
  float* Sa = (float*)so; so += nstate * 4;
  float* Sb = (float*)so; so += nstate * 4;
  float* Sp = (float*)so; so += nstate * 4;
  float* Ia = (float*)so; so += nstate * 4;
  float* Ib = (float*)so; so += nstate * 4;
  float* Ip = (float*)so; so += nstate * 4;

  dim3 blk(256);
  dim3 blk8(512);
  const int wkv_grid = (int)(nstate / 2 / 256);   // 1024

  mix_castw_kernel<<<MIX_BLOCKS + 64, blk, 0, stream>>>(
      x, tmk, tmv, tmr, xkb, xvb, xrb,
      Wk, Wv, Wr, Wo, Wkb, Wvb, Wrb, Wob);
  gemm8_kvr<<<768, blk8, 0, stream>>>(xkb, xvb, xrb, Wkb, Wvb, Wrb,
                                      kbuf, vbuf, rbuf);

  wkv_phase1<<<wkv_grid, blk, 0, stream>>>(kbuf, vbuf, tdec, Sa, Sb, Sp);
  wkv_phase2<<<(BB * CC + 255) / 256, blk, 0, stream>>>(tdec, Sa, Sb, Sp, Ia, Ib, Ip);
  wkv_phase3<<<wkv_grid, blk, 0, stream>>>(kbuf, vbuf, rbuf, tdec, tfir,
                                           Ia, Ib, Ip, rbuf);  // in-place gate

  gemm8_one<<<256, blk8, 0, stream>>>(rbuf, Wob, (float*)d_out);
}

// Round 11
// 286.445 us; speedup vs baseline: 1.0003x; 1.0003x over previous
//
#include <hip/hip_runtime.h>

#define BB 8
#define TT 2048
#define CC 1024
#define WKV_L 32
#define WKV_NCH (TT / WKV_L)   // 64 chunks
#define WKV_LOG_NCH 6

typedef __bf16 bf16x8_t __attribute__((ext_vector_type(8)));
typedef float f32x4_t __attribute__((ext_vector_type(4)));
typedef unsigned short ushort8_t __attribute__((ext_vector_type(8)));

__device__ __forceinline__ unsigned short f2bf(float f) {
  unsigned u = __float_as_uint(f);
  u += 0x7fffu + ((u >> 16) & 1u);   // round-to-nearest-even
  return (unsigned short)(u >> 16);
}
__device__ __forceinline__ float bf2f(unsigned short s) {
  return __uint_as_float(((unsigned)s) << 16);
}

#define GLOAD16(gp, lp)                                                        \
  __builtin_amdgcn_global_load_lds(                                            \
      (const __attribute__((address_space(1))) void*)(gp),                     \
      (__attribute__((address_space(3))) void*)(lp), 16, 0, 0)

// ---- fused mix (block-specialized, XCD-ALIGNED slab sharing) + casts ----
// Dispatch round-robins XCD = bid%8. Decode so the 3 blocks (xk/xv/xr) of a
// slab share bid%8 -> same XCD L2 -> x slab fetched from HBM once:
//   xcd = bid&7; rem = bid>>3; which = rem%3; slab = xcd*128 + rem/3.
// Blocks [3072,3136): the 4 weight casts.
#define MIX_BLOCKS 3072
#define SLAB8 2048            // ushort8 groups per slab (16384 elems = 64 KB)

__global__ __launch_bounds__(256) void mix_castw_kernel(
    const float* __restrict__ x, const float* __restrict__ tmk,
    const float* __restrict__ tmv, const float* __restrict__ tmr,
    unsigned short* __restrict__ xk, unsigned short* __restrict__ xv,
    unsigned short* __restrict__ xr,
    const float* __restrict__ w0, const float* __restrict__ w1,
    const float* __restrict__ w2, const float* __restrict__ w3,
    unsigned short* __restrict__ o0, unsigned short* __restrict__ o1,
    unsigned short* __restrict__ o2, unsigned short* __restrict__ o3) {
  const int bid = blockIdx.x;
  const int tid = threadIdx.x;
  if (bid < MIX_BLOCKS) {
    const int xcd = bid & 7;
    const int rem = bid >> 3;          // 0..383
    const int which = rem % 3;
    const int slab = xcd * 128 + rem / 3;   // 0..1023, same-XCD triples
    const float* tm = which == 0 ? tmk : which == 1 ? tmv : tmr;
    unsigned short* out = which == 0 ? xk : which == 1 ? xv : xr;
#pragma unroll 2
    for (int it = 0; it < SLAB8 / 256; ++it) {
      size_t idx8 = (size_t)slab * SLAB8 + it * 256 + tid;
      size_t e = idx8 * 8;
      int c = (int)(e & (CC - 1));
      int t = (int)((e >> 10) & (TT - 1));
      float4 xa = *(const float4*)(x + e);
      float4 xb = *(const float4*)(x + e + 4);
      float4 pa = make_float4(0.f, 0.f, 0.f, 0.f), pb = pa;
      if (t > 0) {
        pa = *(const float4*)(x + e - CC);
        pb = *(const float4*)(x + e - CC + 4);
      }
      float4 ma = *(const float4*)(tm + c);
      float4 mb = *(const float4*)(tm + c + 4);
      ushort8_t o;
      o[0] = f2bf(xa.x * ma.x + pa.x * (1.f - ma.x));
      o[1] = f2bf(xa.y * ma.y + pa.y * (1.f - ma.y));
      o[2] = f2bf(xa.z * ma.z + pa.z * (1.f - ma.z));
      o[3] = f2bf(xa.w * ma.w + pa.w * (1.f - ma.w));
      o[4] = f2bf(xb.x * mb.x + pb.x * (1.f - mb.x));
      o[5] = f2bf(xb.y * mb.y + pb.y * (1.f - mb.y));
      o[6] = f2bf(xb.z * mb.z + pb.z * (1.f - mb.z));
      o[7] = f2bf(xb.w * mb.w + pb.w * (1.f - mb.w));
      *(ushort8_t*)(out + e) = o;
    }
  } else {
    const int n4 = CC * CC / 4;   // per weight
    for (int i = (bid - MIX_BLOCKS) * 256 + tid; i < 4 * n4;
         i += (gridDim.x - MIX_BLOCKS) * 256) {
      int sel = i / n4;
      int j = i - sel * n4;
      const float* w = sel == 0 ? w0 : sel == 1 ? w1 : sel == 2 ? w2 : w3;
      unsigned short* o = sel == 0 ? o0 : sel == 1 ? o1 : sel == 2 ? o2 : o3;
      float4 v = ((const float4*)w)[j];
      ushort4 u;
      u.x = f2bf(v.x); u.y = f2bf(v.y); u.z = f2bf(v.z); u.w = f2bf(v.w);
      ((ushort4*)o)[j] = u;
    }
  }
}

// ---- 256x256 8-phase GEMM (T2+T3+T4+T5) ---------------------------------
#define NT8 (CC / 64)   // 16 K-tiles

template <typename EPI>
__device__ __forceinline__ void gemm8_body(unsigned short* lds8,
                                           const unsigned short* __restrict__ A,
                                           const unsigned short* __restrict__ Bm,
                                           int tm, int tn, EPI epi) {
  const int tid = threadIdx.x;
  const int lane = tid & 63;
  const int wid = tid >> 6;
  const int wr = wid >> 2;   // 0..1
  const int wc = wid & 3;    // 0..3
  const int fr = lane & 15;
  const int fk = lane >> 4;  // 0..3

  const int srow = tid >> 3;                          // 0..63
  const int gcol = (((tid & 7) ^ (srow & 7)) << 3);   // pre-swizzled global col
  const unsigned short* Ag = A + (size_t)(tm * 256 + srow) * CC + gcol;
  const unsigned short* Bg = Bm + (size_t)(tn * 256 + srow) * CC + gcol;
  const int ldst = tid << 3;                          // linear LDS dest (elems)

  const int rowA = wr * 16 + fr;
  const int rowB = wc * 16 + fr;
  const int sx0 = ((fk ^ (fr & 7)) << 3);             // read-side un-swizzle, kk=0
  const int sx1 = (((4 + fk) ^ (fr & 7)) << 3);       // kk=1

  bf16x8_t aF[4][2];      // current mh half: [i][kk]
  bf16x8_t bF[2][2][2];   // both nh halves:  [nh][j][kk]
  f32x4_t acc[8][4] = {};

#define STG_A(T, H)                                                            \
  {                                                                            \
    const unsigned short* g_ = Ag + (size_t)((H) * 128) * CC + (T) * 64;       \
    unsigned short* l_ = &lds8[(((T) & 1) << 14) + (H) * 8192 + ldst];         \
    GLOAD16(g_, l_);                                                           \
    GLOAD16(g_ + (size_t)64 * CC, l_ + 4096);                                  \
  }
#define STG_B(T, H)                                                            \
  {                                                                            \
    const unsigned short* g_ = Bg + (size_t)((H) * 128) * CC + (T) * 64;       \
    unsigned short* l_ = &lds8[32768 + (((T) & 1) << 14) + (H) * 8192 + ldst]; \
    GLOAD16(g_, l_);                                                           \
    GLOAD16(g_ + (size_t)64 * CC, l_ + 4096);                                  \
  }
#define LOADA(MH)                                                              \
  _Pragma("unroll") for (int i_ = 0; i_ < 4; ++i_) {                           \
    aF[i_][0] = *(const bf16x8_t*)&lds8[ab + ((MH) * 4 + i_) * 2048 + sx0];    \
    aF[i_][1] = *(const bf16x8_t*)&lds8[ab + ((MH) * 4 + i_) * 2048 + sx1];    \
  }
#define LOADB(NH)                                                              \
  _Pragma("unroll") for (int j_ = 0; j_ < 2; ++j_) {                           \
    bF[NH][j_][0] = *(const bf16x8_t*)&lds8[bb + ((NH) * 2 + j_) * 4096 + sx0];\
    bF[NH][j_][1] = *(const bf16x8_t*)&lds8[bb + ((NH) * 2 + j_) * 4096 + sx1];\
  }
#define MFMAQ(MH, NH)                                                          \
  _Pragma("unroll") for (int i_ = 0; i_ < 4; ++i_)                             \
  _Pragma("unroll") for (int j_ = 0; j_ < 2; ++j_) {                           \
    acc[(MH) * 4 + i_][(NH) * 2 + j_] = __builtin_amdgcn_mfma_f32_16x16x32_bf16( \
        aF[i_][0], bF[NH][j_][0], acc[(MH) * 4 + i_][(NH) * 2 + j_], 0, 0, 0); \
    acc[(MH) * 4 + i_][(NH) * 2 + j_] = __builtin_amdgcn_mfma_f32_16x16x32_bf16( \
        aF[i_][1], bF[NH][j_][1], acc[(MH) * 4 + i_][(NH) * 2 + j_], 0, 0, 0); \
  }

  STG_A(0, 0) STG_B(0, 0) STG_A(0, 1) STG_B(0, 1)
  STG_A(1, 0) STG_B(1, 0) STG_A(1, 1)
  asm volatile("s_waitcnt vmcnt(10)" ::: "memory");
  __builtin_amdgcn_s_barrier();

#pragma unroll
  for (int t = 0; t < NT8; ++t) {
    const int ab = ((t & 1) << 14) + rowA * 64;
    const int bb = 32768 + ((t & 1) << 14) + rowB * 64;
    LOADA(0) LOADB(0)
    if (t + 1 < NT8) { STG_B(t + 1, 1) }
    asm volatile("s_waitcnt vmcnt(8)" ::: "memory");
    __builtin_amdgcn_s_barrier();
    __builtin_amdgcn_s_setprio(1);
    MFMAQ(0, 0)
    __builtin_amdgcn_s_setprio(0);
    __builtin_amdgcn_s_barrier();
    LOADB(1)
    if (t + 2 < NT8) { STG_A(t + 2, 0) }
    __builtin_amdgcn_s_barrier();
    __builtin_amdgcn_s_setprio(1);
    MFMAQ(0, 1)
    __builtin_amdgcn_s_setprio(0);
    __builtin_amdgcn_s_barrier();
    LOADA(1)
    if (t + 2 < NT8) { STG_B(t + 2, 0) }
    __builtin_amdgcn_s_barrier();
    __builtin_amdgcn_s_setprio(1);
    MFMAQ(1, 0)
    __builtin_amdgcn_s_setprio(0);
    __builtin_amdgcn_s_barrier();
    if (t + 2 < NT8) { STG_A(t + 2, 1) }
    asm volatile("s_waitcnt vmcnt(10)" ::: "memory");
    __builtin_amdgcn_s_barrier();
    __builtin_amdgcn_s_setprio(1);
    MFMAQ(1, 1)
    __builtin_amdgcn_s_setprio(0);
    __builtin_amdgcn_s_barrier();
  }

#pragma unroll
  for (int im = 0; im < 8; ++im)
#pragma unroll
    for (int jn = 0; jn < 4; ++jn)
#pragma unroll
      for (int rg = 0; rg < 4; ++rg)
        epi((size_t)(tm * 256 + wr * 16 + im * 32 + (fk << 2) + rg) * CC +
                (size_t)(tn * 256 + wc * 16 + jn * 64 + fr),
            acc[im][jn][rg]);
#undef STG_A
#undef STG_B
#undef LOADA
#undef LOADB
#undef MFMAQ
}

// merged k/v/r projection: 768 blocks, XCD-swizzled, all outputs bf16
__global__ __launch_bounds__(512, 2) void gemm8_kvr(
    const unsigned short* __restrict__ xk, const unsigned short* __restrict__ xv,
    const unsigned short* __restrict__ xr, const unsigned short* __restrict__ Wk,
    const unsigned short* __restrict__ Wv, const unsigned short* __restrict__ Wr,
    unsigned short* __restrict__ kout, unsigned short* __restrict__ vout,
    unsigned short* __restrict__ rout) {
  __shared__ unsigned short lds8[65536];   // 128 KB
  int orig = blockIdx.x;
  int wg = (orig & 7) * 96 + (orig >> 3);
  int which = wg >> 8;        // 256 tiles per matrix
  int rr = wg & 255;
  int tm = rr >> 2;           // tn-fast within XCD chunk
  int tn = rr & 3;
  const unsigned short* A = which == 0 ? xk : which == 1 ? xv : xr;
  const unsigned short* Bm = which == 0 ? Wk : which == 1 ? Wv : Wr;
  unsigned short* o = which == 0 ? kout : which == 1 ? vout : rout;
  gemm8_body(lds8, A, Bm, tm, tn,
             [&](size_t off, float val) { o[off] = f2bf(val); });
}

// single GEMM (256 blocks, XCD-swizzled), fp32 out (final projection)
__global__ __launch_bounds__(512, 2) void gemm8_one(const unsigned short* __restrict__ A,
                         const unsigned short* __restrict__ Bm,
                         float* __restrict__ Cm) {
  __shared__ unsigned short lds8[65536];   // 128 KB
  int orig = blockIdx.x;
  int wg = (orig & 7) * 32 + (orig >> 3);
  int tm = wg >> 2;
  int tn = wg & 3;
  gemm8_body(lds8, A, Bm, tm, tn,
             [&](size_t off, float val) { Cm[off] = val; });
}

// ---- Chunk-parallel WKV scan, anchor-decay, 2 ch/thread, load pipeline ---
__global__ __launch_bounds__(256) void wkv_phase1(const unsigned short* __restrict__ k,
                           const unsigned short* __restrict__ v,
                           const float* __restrict__ wdec,
                           float* __restrict__ Sa, float* __restrict__ Sb,
                           float* __restrict__ Sp) {
  int idx = blockIdx.x * blockDim.x + threadIdx.x;  // (b*NCH + j)*(CC/2) + c2
  int c = (idx & (CC / 2 - 1)) << 1;
  int bj = idx >> 9;
  int j = bj & (WKV_NCH - 1);
  int b = bj >> WKV_LOG_NCH;
  float w0 = -__expf(wdec[c]), w1 = -__expf(wdec[c + 1]);
  size_t off = ((size_t)b * TT + (size_t)j * WKV_L) * CC + c;
  float aa0 = 0.f, bb0 = 0.f, pp0 = -1e38f;
  float aa1 = 0.f, bb1 = 0.f, pp1 = -1e38f;
  ushort2 kk = *(const ushort2*)(k + off);
  ushort2 vv = *(const ushort2*)(v + off);
  for (int t = 0; t < WKV_L; ++t) {
    size_t noff = off + ((t + 1 < WKV_L) ? CC : 0);
    ushort2 nk = *(const ushort2*)(k + noff);
    ushort2 nv = *(const ushort2*)(v + noff);
    float k0 = bf2f(kk.x), k1 = bf2f(kk.y);
    float v0 = bf2f(vv.x), v1 = bf2f(vv.y);
    pp0 += w0; pp1 += w1;
    float d0 = k0 - pp0, d1 = k1 - pp1;
    if (d0 > 8.f) { float s = __expf(-d0); aa0 *= s; bb0 *= s; pp0 = k0; d0 = 0.f; }
    if (d1 > 8.f) { float s = __expf(-d1); aa1 *= s; bb1 *= s; pp1 = k1; d1 = 0.f; }
    float E0 = __expf(d0), E1 = __expf(d1);
    aa0 = fmaf(E0, v0, aa0); bb0 += E0;
    aa1 = fmaf(E1, v1, aa1); bb1 += E1;
    kk = nk; vv = nv; off = noff;
  }
  size_t s = (size_t)bj * CC + c;
  *(float2*)(Sa + s) = make_float2(aa0, aa1);
  *(float2*)(Sb + s) = make_float2(bb0, bb1);
  *(float2*)(Sp + s) = make_float2(pp0, pp1);
}

// serial scan over chunk summaries -> incoming state per chunk
__global__ __launch_bounds__(256) void wkv_phase2(const float* __restrict__ wdec,
                           const float* __restrict__ Sa, const float* __restrict__ Sb,
                           const float* __restrict__ Sp,
                           float* __restrict__ Ia, float* __restrict__ Ib,
                           float* __restrict__ Ip) {
  int idx = blockIdx.x * blockDim.x + threadIdx.x;  // b*CC + c
  if (idx >= BB * CC) return;
  int c = idx & (CC - 1);
  int b = idx >> 10;
  float wL = -__expf(wdec[c]) * (float)WKV_L;
  float aa = 0.f, bb = 0.f, pp = -1e38f;
  for (int j = 0; j < WKV_NCH; ++j) {
    size_t s = (size_t)(b * WKV_NCH + j) * CC + c;
    Ia[s] = aa; Ib[s] = bb; Ip[s] = pp;
    float pd = pp + wL;
    float ps = Sp[s];
    float q = fmaxf(pd, ps);
    float e1 = __expf(pd - q);
    float e2 = __expf(ps - q);
    aa = fmaf(e1, aa, e2 * Sa[s]);
    bb = fmaf(e1, bb, e2 * Sb[s]);
    pp = q;
  }
}

// phase3: anchor-decay replay + fused sigmoid(r)*y, 2 ch/thread, in-place,
// with t+1 load prefetch.
__global__ __launch_bounds__(256) void wkv_phase3(const unsigned short* __restrict__ k,
                           const unsigned short* __restrict__ v,
                           const unsigned short* r,
                           const float* __restrict__ wdec,
                           const float* __restrict__ u,
                           const float* __restrict__ Ia, const float* __restrict__ Ib,
                           const float* __restrict__ Ip,
                           unsigned short* out) {
  int idx = blockIdx.x * blockDim.x + threadIdx.x;
  int c = (idx & (CC / 2 - 1)) << 1;
  int bj = idx >> 9;
  int j = bj & (WKV_NCH - 1);
  int b = bj >> WKV_LOG_NCH;
  float w0 = -__expf(wdec[c]), w1 = -__expf(wdec[c + 1]);
  float u0 = u[c], u1 = u[c + 1];
  size_t st = (size_t)bj * CC + c;
  float2 a2 = *(const float2*)(Ia + st);
  float2 b2 = *(const float2*)(Ib + st);
  float2 p2 = *(const float2*)(Ip + st);
  float aa0 = a2.x, bb0 = b2.x, pp0 = p2.x;
  float aa1 = a2.y, bb1 = b2.y, pp1 = p2.y;
  size_t off = ((size_t)b * TT + (size_t)j * WKV_L) * CC + c;
  ushort2 kk = *(const ushort2*)(k + off);
  ushort2 vv = *(const ushort2*)(v + off);
  ushort2 rr2 = *(const ushort2*)(r + off);
  for (int t = 0; t < WKV_L; ++t) {
    size_t noff = off + ((t + 1 < WKV_L) ? CC : 0);
    ushort2 nk = *(const ushort2*)(k + noff);
    ushort2 nv = *(const ushort2*)(v + noff);
    ushort2 nr = *(const ushort2*)(r + noff);
    float k0 = bf2f(kk.x), k1 = bf2f(kk.y);
    float v0 = bf2f(vv.x), v1 = bf2f(vv.y);
    // y from pre-decay state
    float dy0 = fminf(u0 + k0 - pp0, 60.f);
    float dy1 = fminf(u1 + k1 - pp1, 60.f);
    float Eu0 = __expf(dy0), Eu1 = __expf(dy1);
    float y0 = fmaf(Eu0, v0, aa0) / (bb0 + Eu0);
    float y1 = fmaf(Eu1, v1, aa1) / (bb1 + Eu1);
    float sr0 = 1.f / (1.f + __expf(-bf2f(rr2.x)));
    float sr1 = 1.f / (1.f + __expf(-bf2f(rr2.y)));
    ushort2 o;
    o.x = f2bf(sr0 * y0);
    o.y = f2bf(sr1 * y1);
    *(ushort2*)(out + off) = o;
    // decay + rare renorm + accumulate
    pp0 += w0; pp1 += w1;
    float d0 = k0 - pp0, d1 = k1 - pp1;
    if (d0 > 8.f) { float s = __expf(-d0); aa0 *= s; bb0 *= s; pp0 = k0; d0 = 0.f; }
    if (d1 > 8.f) { float s = __expf(-d1); aa1 *= s; bb1 *= s; pp1 = k1; d1 = 0.f; }
    float E0 = __expf(d0), E1 = __expf(d1);
    aa0 = fmaf(E0, v0, aa0); bb0 += E0;
    aa1 = fmaf(E1, v1, aa1); bb1 += E1;
    kk = nk; vv = nv; rr2 = nr; off = noff;
  }
}

extern "C" void kernel_launch(void* const* d_in, const int* in_sizes, int n_in,
                              void* d_out, int out_size, void* d_ws, size_t ws_size,
                              hipStream_t stream) {
  const float* x    = (const float*)d_in[0];
  const float* tdec = (const float*)d_in[1];
  const float* tfir = (const float*)d_in[2];
  const float* tmk  = (const float*)d_in[3];
  const float* tmv  = (const float*)d_in[4];
  const float* tmr  = (const float*)d_in[5];
  const float* Wk   = (const float*)d_in[6];
  const float* Wv   = (const float*)d_in[7];
  const float* Wr   = (const float*)d_in[8];
  const float* Wo   = (const float*)d_in[9];

  const size_t M = (size_t)BB * TT;     // 16384
  const size_t mixbytes = M * CC * 2;   // 33.5 MB
  const size_t wbytes = (size_t)CC * CC * 2;
  const size_t nstate = (size_t)BB * WKV_NCH * CC;   // 512K

  // Layout (~209 MB peak, proven fit):
  char* ws = (char*)d_ws;
  unsigned short* xkb = (unsigned short*)ws;  ws += mixbytes;
  unsigned short* xvb = (unsigned short*)ws;  ws += mixbytes;
  unsigned short* xrb = (unsigned short*)ws;  ws += mixbytes;
  unsigned short* Wkb = (unsigned short*)ws; ws += wbytes;
  unsigned short* Wvb = (unsigned short*)ws; ws += wbytes;
  unsigned short* Wrb = (unsigned short*)ws; ws += wbytes;
  unsigned short* Wob = (unsigned short*)ws; ws += wbytes;
  unsigned short* kbuf = (unsigned short*)ws; ws += mixbytes;
  unsigned short* vbuf = (unsigned short*)ws; ws += mixbytes;
  unsigned short* rbuf = (unsigned short*)ws; ws += mixbytes;
  // states overlay the dead xk/xv regions (12.6 MB < 67 MB)
  char* so = (char*)xkb;
  float* Sa = (float*)so; so += nstate * 4;
  float* Sb = (float*)so; so += nstate * 4;
  float* Sp = (float*)so; so += nstate * 4;
  float* Ia = (float*)so; so += nstate * 4;
  float* Ib = (float*)so; so += nstate * 4;
  float* Ip = (float*)so; so += nstate * 4;

  dim3 blk(256);
  dim3 blk8(512);
  const int wkv_grid = (int)(nstate / 2 / 256);   // 1024

  mix_castw_kernel<<<MIX_BLOCKS + 64, blk, 0, stream>>>(
      x, tmk, tmv, tmr, xkb, xvb, xrb,
      Wk, Wv, Wr, Wo, Wkb, Wvb, Wrb, Wob);
  gemm8_kvr<<<768, blk8, 0, stream>>>(xkb, xvb, xrb, Wkb, Wvb, Wrb,
                                      kbuf, vbuf, rbuf);

  wkv_phase1<<<wkv_grid, blk, 0, stream>>>(kbuf, vbuf, tdec, Sa, Sb, Sp);
  wkv_phase2<<<(BB * CC + 255) / 256, blk, 0, stream>>>(tdec, Sa, Sb, Sp, Ia, Ib, Ip);
  wkv_phase3<<<wkv_grid, blk, 0, stream>>>(kbuf, vbuf, rbuf, tdec, tfir,
                                           Ia, Ib, Ip, rbuf);  // in-place gate

  gemm8_one<<<256, blk8, 0, stream>>>(rbuf, Wob, (float*)d_out);
}

// Round 12
// 238.760 us; speedup vs baseline: 1.2001x; 1.1997x over previous
//
#include <hip/hip_runtime.h>

#define BB 8
#define TT 2048
#define CC 1024
#define WKV_L 32
#define WKV_NCH (TT / WKV_L)   // 64 chunks
#define WKV_LOG_NCH 6

typedef __bf16 bf16x8_t __attribute__((ext_vector_type(8)));
typedef float f32x4_t __attribute__((ext_vector_type(4)));
typedef unsigned short ushort8_t __attribute__((ext_vector_type(8)));

__device__ __forceinline__ unsigned short f2bf(float f) {
  unsigned u = __float_as_uint(f);
  u += 0x7fffu + ((u >> 16) & 1u);   // round-to-nearest-even
  return (unsigned short)(u >> 16);
}
__device__ __forceinline__ float bf2f(unsigned short s) {
  return __uint_as_float(((unsigned)s) << 16);
}

#define GLOAD16(gp, lp)                                                        \
  __builtin_amdgcn_global_load_lds(                                            \
      (const __attribute__((address_space(1))) void*)(gp),                     \
      (__attribute__((address_space(3))) void*)(lp), 16, 0, 0)

// ---- fused mix3 (R9 grid-stride form, proven 46.5 us) + weight casts ----
// Blocks [0,MIXGRID): grid-stride mix3 (all 3 outputs per thread -> x read
// once, loads pipeline across grid-stride iterations).
// Blocks [MIXGRID, MIXGRID+CASTGRID): the 4 weight casts (per-block work
// matched to mix blocks so neither is the tail).
#define MIXGRID 2048
#define CASTGRID 256

__global__ __launch_bounds__(256) void mix3_castw_kernel(
    const float* __restrict__ x, const float* __restrict__ tmk,
    const float* __restrict__ tmv, const float* __restrict__ tmr,
    unsigned short* __restrict__ xk, unsigned short* __restrict__ xv,
    unsigned short* __restrict__ xr,
    const float* __restrict__ w0, const float* __restrict__ w1,
    const float* __restrict__ w2, const float* __restrict__ w3,
    unsigned short* __restrict__ o0, unsigned short* __restrict__ o1,
    unsigned short* __restrict__ o2, unsigned short* __restrict__ o3) {
  const int bid = blockIdx.x;
  const int tid = threadIdx.x;
  if (bid < MIXGRID) {
    const size_t total8 = (size_t)BB * TT * CC / 8;
    for (size_t i = (size_t)bid * 256 + tid; i < total8;
         i += (size_t)MIXGRID * 256) {
      size_t e = i * 8;
      int c = (int)(e & (CC - 1));
      int t = (int)((e >> 10) & (TT - 1));
      float4 xa = *(const float4*)(x + e);
      float4 xb = *(const float4*)(x + e + 4);
      float4 pa = make_float4(0.f, 0.f, 0.f, 0.f), pb = pa;
      if (t > 0) {
        pa = *(const float4*)(x + e - CC);
        pb = *(const float4*)(x + e - CC + 4);
      }
      float4 mka = *(const float4*)(tmk + c), mkb = *(const float4*)(tmk + c + 4);
      float4 mva = *(const float4*)(tmv + c), mvb = *(const float4*)(tmv + c + 4);
      float4 mra = *(const float4*)(tmr + c), mrb = *(const float4*)(tmr + c + 4);
      ushort8_t ok, ov, orr;
#define MIX1(dst, idx, xv_, pv_, m_) dst[idx] = f2bf(xv_ * m_ + pv_ * (1.f - m_));
      MIX1(ok, 0, xa.x, pa.x, mka.x) MIX1(ok, 1, xa.y, pa.y, mka.y)
      MIX1(ok, 2, xa.z, pa.z, mka.z) MIX1(ok, 3, xa.w, pa.w, mka.w)
      MIX1(ok, 4, xb.x, pb.x, mkb.x) MIX1(ok, 5, xb.y, pb.y, mkb.y)
      MIX1(ok, 6, xb.z, pb.z, mkb.z) MIX1(ok, 7, xb.w, pb.w, mkb.w)
      MIX1(ov, 0, xa.x, pa.x, mva.x) MIX1(ov, 1, xa.y, pa.y, mva.y)
      MIX1(ov, 2, xa.z, pa.z, mva.z) MIX1(ov, 3, xa.w, pa.w, mva.w)
      MIX1(ov, 4, xb.x, pb.x, mvb.x) MIX1(ov, 5, xb.y, pb.y, mvb.y)
      MIX1(ov, 6, xb.z, pb.z, mvb.z) MIX1(ov, 7, xb.w, pb.w, mvb.w)
      MIX1(orr, 0, xa.x, pa.x, mra.x) MIX1(orr, 1, xa.y, pa.y, mra.y)
      MIX1(orr, 2, xa.z, pa.z, mra.z) MIX1(orr, 3, xa.w, pa.w, mra.w)
      MIX1(orr, 4, xb.x, pb.x, mrb.x) MIX1(orr, 5, xb.y, pb.y, mrb.y)
      MIX1(orr, 6, xb.z, pb.z, mrb.z) MIX1(orr, 7, xb.w, pb.w, mrb.w)
#undef MIX1
      *(ushort8_t*)(xk + e) = ok;
      *(ushort8_t*)(xv + e) = ov;
      *(ushort8_t*)(xr + e) = orr;
    }
  } else {
    const int n4 = CC * CC / 4;   // per weight
    for (int i = (bid - MIXGRID) * 256 + tid; i < 4 * n4;
         i += CASTGRID * 256) {
      int sel = i / n4;
      int j = i - sel * n4;
      const float* w = sel == 0 ? w0 : sel == 1 ? w1 : sel == 2 ? w2 : w3;
      unsigned short* o = sel == 0 ? o0 : sel == 1 ? o1 : sel == 2 ? o2 : o3;
      float4 v = ((const float4*)w)[j];
      ushort4 u;
      u.x = f2bf(v.x); u.y = f2bf(v.y); u.z = f2bf(v.z); u.w = f2bf(v.w);
      ((ushort4*)o)[j] = u;
    }
  }
}

// ---- 256x256 8-phase GEMM (T2+T3+T4+T5) ---------------------------------
#define NT8 (CC / 64)   // 16 K-tiles

template <typename EPI>
__device__ __forceinline__ void gemm8_body(unsigned short* lds8,
                                           const unsigned short* __restrict__ A,
                                           const unsigned short* __restrict__ Bm,
                                           int tm, int tn, EPI epi) {
  const int tid = threadIdx.x;
  const int lane = tid & 63;
  const int wid = tid >> 6;
  const int wr = wid >> 2;   // 0..1
  const int wc = wid & 3;    // 0..3
  const int fr = lane & 15;
  const int fk = lane >> 4;  // 0..3

  const int srow = tid >> 3;                          // 0..63
  const int gcol = (((tid & 7) ^ (srow & 7)) << 3);   // pre-swizzled global col
  const unsigned short* Ag = A + (size_t)(tm * 256 + srow) * CC + gcol;
  const unsigned short* Bg = Bm + (size_t)(tn * 256 + srow) * CC + gcol;
  const int ldst = tid << 3;                          // linear LDS dest (elems)

  const int rowA = wr * 16 + fr;
  const int rowB = wc * 16 + fr;
  const int sx0 = ((fk ^ (fr & 7)) << 3);             // read-side un-swizzle, kk=0
  const int sx1 = (((4 + fk) ^ (fr & 7)) << 3);       // kk=1

  bf16x8_t aF[4][2];      // current mh half: [i][kk]
  bf16x8_t bF[2][2][2];   // both nh halves:  [nh][j][kk]
  f32x4_t acc[8][4] = {};

#define STG_A(T, H)                                                            \
  {                                                                            \
    const unsigned short* g_ = Ag + (size_t)((H) * 128) * CC + (T) * 64;       \
    unsigned short* l_ = &lds8[(((T) & 1) << 14) + (H) * 8192 + ldst];         \
    GLOAD16(g_, l_);                                                           \
    GLOAD16(g_ + (size_t)64 * CC, l_ + 4096);                                  \
  }
#define STG_B(T, H)                                                            \
  {                                                                            \
    const unsigned short* g_ = Bg + (size_t)((H) * 128) * CC + (T) * 64;       \
    unsigned short* l_ = &lds8[32768 + (((T) & 1) << 14) + (H) * 8192 + ldst]; \
    GLOAD16(g_, l_);                                                           \
    GLOAD16(g_ + (size_t)64 * CC, l_ + 4096);                                  \
  }
#define LOADA(MH)                                                              \
  _Pragma("unroll") for (int i_ = 0; i_ < 4; ++i_) {                           \
    aF[i_][0] = *(const bf16x8_t*)&lds8[ab + ((MH) * 4 + i_) * 2048 + sx0];    \
    aF[i_][1] = *(const bf16x8_t*)&lds8[ab + ((MH) * 4 + i_) * 2048 + sx1];    \
  }
#define LOADB(NH)                                                              \
  _Pragma("unroll") for (int j_ = 0; j_ < 2; ++j_) {                           \
    bF[NH][j_][0] = *(const bf16x8_t*)&lds8[bb + ((NH) * 2 + j_) * 4096 + sx0];\
    bF[NH][j_][1] = *(const bf16x8_t*)&lds8[bb + ((NH) * 2 + j_) * 4096 + sx1];\
  }
#define MFMAQ(MH, NH)                                                          \
  _Pragma("unroll") for (int i_ = 0; i_ < 4; ++i_)                             \
  _Pragma("unroll") for (int j_ = 0; j_ < 2; ++j_) {                           \
    acc[(MH) * 4 + i_][(NH) * 2 + j_] = __builtin_amdgcn_mfma_f32_16x16x32_bf16( \
        aF[i_][0], bF[NH][j_][0], acc[(MH) * 4 + i_][(NH) * 2 + j_], 0, 0, 0); \
    acc[(MH) * 4 + i_][(NH) * 2 + j_] = __builtin_amdgcn_mfma_f32_16x16x32_bf16( \
        aF[i_][1], bF[NH][j_][1], acc[(MH) * 4 + i_][(NH) * 2 + j_], 0, 0, 0); \
  }

  STG_A(0, 0) STG_B(0, 0) STG_A(0, 1) STG_B(0, 1)
  STG_A(1, 0) STG_B(1, 0) STG_A(1, 1)
  asm volatile("s_waitcnt vmcnt(10)" ::: "memory");
  __builtin_amdgcn_s_barrier();

#pragma unroll
  for (int t = 0; t < NT8; ++t) {
    const int ab = ((t & 1) << 14) + rowA * 64;
    const int bb = 32768 + ((t & 1) << 14) + rowB * 64;
    LOADA(0) LOADB(0)
    if (t + 1 < NT8) { STG_B(t + 1, 1) }
    asm volatile("s_waitcnt vmcnt(8)" ::: "memory");
    __builtin_amdgcn_s_barrier();
    __builtin_amdgcn_s_setprio(1);
    MFMAQ(0, 0)
    __builtin_amdgcn_s_setprio(0);
    __builtin_amdgcn_s_barrier();
    LOADB(1)
    if (t + 2 < NT8) { STG_A(t + 2, 0) }
    __builtin_amdgcn_s_barrier();
    __builtin_amdgcn_s_setprio(1);
    MFMAQ(0, 1)
    __builtin_amdgcn_s_setprio(0);
    __builtin_amdgcn_s_barrier();
    LOADA(1)
    if (t + 2 < NT8) { STG_B(t + 2, 0) }
    __builtin_amdgcn_s_barrier();
    __builtin_amdgcn_s_setprio(1);
    MFMAQ(1, 0)
    __builtin_amdgcn_s_setprio(0);
    __builtin_amdgcn_s_barrier();
    if (t + 2 < NT8) { STG_A(t + 2, 1) }
    asm volatile("s_waitcnt vmcnt(10)" ::: "memory");
    __builtin_amdgcn_s_barrier();
    __builtin_amdgcn_s_setprio(1);
    MFMAQ(1, 1)
    __builtin_amdgcn_s_setprio(0);
    __builtin_amdgcn_s_barrier();
  }

#pragma unroll
  for (int im = 0; im < 8; ++im)
#pragma unroll
    for (int jn = 0; jn < 4; ++jn)
#pragma unroll
      for (int rg = 0; rg < 4; ++rg)
        epi((size_t)(tm * 256 + wr * 16 + im * 32 + (fk << 2) + rg) * CC +
                (size_t)(tn * 256 + wc * 16 + jn * 64 + fr),
            acc[im][jn][rg]);
#undef STG_A
#undef STG_B
#undef LOADA
#undef LOADB
#undef MFMAQ
}

// merged k/v/r projection: 768 blocks, XCD-swizzled, all outputs bf16
__global__ __launch_bounds__(512, 2) void gemm8_kvr(
    const unsigned short* __restrict__ xk, const unsigned short* __restrict__ xv,
    const unsigned short* __restrict__ xr, const unsigned short* __restrict__ Wk,
    const unsigned short* __restrict__ Wv, const unsigned short* __restrict__ Wr,
    unsigned short* __restrict__ kout, unsigned short* __restrict__ vout,
    unsigned short* __restrict__ rout) {
  __shared__ unsigned short lds8[65536];   // 128 KB
  int orig = blockIdx.x;
  int wg = (orig & 7) * 96 + (orig >> 3);
  int which = wg >> 8;        // 256 tiles per matrix
  int rr = wg & 255;
  int tm = rr >> 2;           // tn-fast within XCD chunk
  int tn = rr & 3;
  const unsigned short* A = which == 0 ? xk : which == 1 ? xv : xr;
  const unsigned short* Bm = which == 0 ? Wk : which == 1 ? Wv : Wr;
  unsigned short* o = which == 0 ? kout : which == 1 ? vout : rout;
  gemm8_body(lds8, A, Bm, tm, tn,
             [&](size_t off, float val) { o[off] = f2bf(val); });
}

// single GEMM (256 blocks, XCD-swizzled), fp32 out (final projection)
__global__ __launch_bounds__(512, 2) void gemm8_one(const unsigned short* __restrict__ A,
                         const unsigned short* __restrict__ Bm,
                         float* __restrict__ Cm) {
  __shared__ unsigned short lds8[65536];   // 128 KB
  int orig = blockIdx.x;
  int wg = (orig & 7) * 32 + (orig >> 3);
  int tm = wg >> 2;
  int tn = wg & 3;
  gemm8_body(lds8, A, Bm, tm, tn,
             [&](size_t off, float val) { Cm[off] = val; });
}

// ---- Chunk-parallel WKV scan, anchor-decay, 2 ch/thread, load pipeline ---
__global__ __launch_bounds__(256) void wkv_phase1(const unsigned short* __restrict__ k,
                           const unsigned short* __restrict__ v,
                           const float* __restrict__ wdec,
                           float* __restrict__ Sa, float* __restrict__ Sb,
                           float* __restrict__ Sp) {
  int idx = blockIdx.x * blockDim.x + threadIdx.x;  // (b*NCH + j)*(CC/2) + c2
  int c = (idx & (CC / 2 - 1)) << 1;
  int bj = idx >> 9;
  int j = bj & (WKV_NCH - 1);
  int b = bj >> WKV_LOG_NCH;
  float w0 = -__expf(wdec[c]), w1 = -__expf(wdec[c + 1]);
  size_t off = ((size_t)b * TT + (size_t)j * WKV_L) * CC + c;
  float aa0 = 0.f, bb0 = 0.f, pp0 = -1e38f;
  float aa1 = 0.f, bb1 = 0.f, pp1 = -1e38f;
  ushort2 kk = *(const ushort2*)(k + off);
  ushort2 vv = *(const ushort2*)(v + off);
  for (int t = 0; t < WKV_L; ++t) {
    size_t noff = off + ((t + 1 < WKV_L) ? CC : 0);
    ushort2 nk = *(const ushort2*)(k + noff);
    ushort2 nv = *(const ushort2*)(v + noff);
    float k0 = bf2f(kk.x), k1 = bf2f(kk.y);
    float v0 = bf2f(vv.x), v1 = bf2f(vv.y);
    pp0 += w0; pp1 += w1;
    float d0 = k0 - pp0, d1 = k1 - pp1;
    if (d0 > 8.f) { float s = __expf(-d0); aa0 *= s; bb0 *= s; pp0 = k0; d0 = 0.f; }
    if (d1 > 8.f) { float s = __expf(-d1); aa1 *= s; bb1 *= s; pp1 = k1; d1 = 0.f; }
    float E0 = __expf(d0), E1 = __expf(d1);
    aa0 = fmaf(E0, v0, aa0); bb0 += E0;
    aa1 = fmaf(E1, v1, aa1); bb1 += E1;
    kk = nk; vv = nv; off = noff;
  }
  size_t s = (size_t)bj * CC + c;
  *(float2*)(Sa + s) = make_float2(aa0, aa1);
  *(float2*)(Sb + s) = make_float2(bb0, bb1);
  *(float2*)(Sp + s) = make_float2(pp0, pp1);
}

// serial scan over chunk summaries -> incoming state per chunk
__global__ __launch_bounds__(256) void wkv_phase2(const float* __restrict__ wdec,
                           const float* __restrict__ Sa, const float* __restrict__ Sb,
                           const float* __restrict__ Sp,
                           float* __restrict__ Ia, float* __restrict__ Ib,
                           float* __restrict__ Ip) {
  int idx = blockIdx.x * blockDim.x + threadIdx.x;  // b*CC + c
  if (idx >= BB * CC) return;
  int c = idx & (CC - 1);
  int b = idx >> 10;
  float wL = -__expf(wdec[c]) * (float)WKV_L;
  float aa = 0.f, bb = 0.f, pp = -1e38f;
  for (int j = 0; j < WKV_NCH; ++j) {
    size_t s = (size_t)(b * WKV_NCH + j) * CC + c;
    Ia[s] = aa; Ib[s] = bb; Ip[s] = pp;
    float pd = pp + wL;
    float ps = Sp[s];
    float q = fmaxf(pd, ps);
    float e1 = __expf(pd - q);
    float e2 = __expf(ps - q);
    aa = fmaf(e1, aa, e2 * Sa[s]);
    bb = fmaf(e1, bb, e2 * Sb[s]);
    pp = q;
  }
}

// phase3: anchor-decay replay + fused sigmoid(r)*y, 2 ch/thread, in-place,
// with t+1 load prefetch.
__global__ __launch_bounds__(256) void wkv_phase3(const unsigned short* __restrict__ k,
                           const unsigned short* __restrict__ v,
                           const unsigned short* r,
                           const float* __restrict__ wdec,
                           const float* __restrict__ u,
                           const float* __restrict__ Ia, const float* __restrict__ Ib,
                           const float* __restrict__ Ip,
                           unsigned short* out) {
  int idx = blockIdx.x * blockDim.x + threadIdx.x;
  int c = (idx & (CC / 2 - 1)) << 1;
  int bj = idx >> 9;
  int j = bj & (WKV_NCH - 1);
  int b = bj >> WKV_LOG_NCH;
  float w0 = -__expf(wdec[c]), w1 = -__expf(wdec[c + 1]);
  float u0 = u[c], u1 = u[c + 1];
  size_t st = (size_t)bj * CC + c;
  float2 a2 = *(const float2*)(Ia + st);
  float2 b2 = *(const float2*)(Ib + st);
  float2 p2 = *(const float2*)(Ip + st);
  float aa0 = a2.x, bb0 = b2.x, pp0 = p2.x;
  float aa1 = a2.y, bb1 = b2.y, pp1 = p2.y;
  size_t off = ((size_t)b * TT + (size_t)j * WKV_L) * CC + c;
  ushort2 kk = *(const ushort2*)(k + off);
  ushort2 vv = *(const ushort2*)(v + off);
  ushort2 rr2 = *(const ushort2*)(r + off);
  for (int t = 0; t < WKV_L; ++t) {
    size_t noff = off + ((t + 1 < WKV_L) ? CC : 0);
    ushort2 nk = *(const ushort2*)(k + noff);
    ushort2 nv = *(const ushort2*)(v + noff);
    ushort2 nr = *(const ushort2*)(r + noff);
    float k0 = bf2f(kk.x), k1 = bf2f(kk.y);
    float v0 = bf2f(vv.x), v1 = bf2f(vv.y);
    // y from pre-decay state
    float dy0 = fminf(u0 + k0 - pp0, 60.f);
    float dy1 = fminf(u1 + k1 - pp1, 60.f);
    float Eu0 = __expf(dy0), Eu1 = __expf(dy1);
    float y0 = fmaf(Eu0, v0, aa0) / (bb0 + Eu0);
    float y1 = fmaf(Eu1, v1, aa1) / (bb1 + Eu1);
    float sr0 = 1.f / (1.f + __expf(-bf2f(rr2.x)));
    float sr1 = 1.f / (1.f + __expf(-bf2f(rr2.y)));
    ushort2 o;
    o.x = f2bf(sr0 * y0);
    o.y = f2bf(sr1 * y1);
    *(ushort2*)(out + off) = o;
    // decay + rare renorm + accumulate
    pp0 += w0; pp1 += w1;
    float d0 = k0 - pp0, d1 = k1 - pp1;
    if (d0 > 8.f) { float s = __expf(-d0); aa0 *= s; bb0 *= s; pp0 = k0; d0 = 0.f; }
    if (d1 > 8.f) { float s = __expf(-d1); aa1 *= s; bb1 *= s; pp1 = k1; d1 = 0.f; }
    float E0 = __expf(d0), E1 = __expf(d1);
    aa0 = fmaf(E0, v0, aa0); bb0 += E0;
    aa1 = fmaf(E1, v1, aa1); bb1 += E1;
    kk = nk; vv = nv; rr2 = nr; off = noff;
  }
}

extern "C" void kernel_launch(void* const* d_in, const int* in_sizes, int n_in,
                              void* d_out, int out_size, void* d_ws, size_t ws_size,
                              hipStream_t stream) {
  const float* x    = (const float*)d_in[0];
  const float* tdec = (const float*)d_in[1];
  const float* tfir = (const float*)d_in[2];
  const float* tmk  = (const float*)d_in[3];
  const float* tmv  = (const float*)d_in[4];
  const float* tmr  = (const float*)d_in[5];
  const float* Wk   = (const float*)d_in[6];
  const float* Wv   = (const float*)d_in[7];
  const float* Wr   = (const float*)d_in[8];
  const float* Wo   = (const float*)d_in[9];

  const size_t M = (size_t)BB * TT;     // 16384
  const size_t mixbytes = M * CC * 2;   // 33.5 MB
  const size_t wbytes = (size_t)CC * CC * 2;
  const size_t nstate = (size_t)BB * WKV_NCH * CC;   // 512K

  // Layout (~209 MB peak, proven fit):
  char* ws = (char*)d_ws;
  unsigned short* xkb = (unsigned short*)ws;  ws += mixbytes;
  unsigned short* xvb = (unsigned short*)ws;  ws += mixbytes;
  unsigned short* xrb = (unsigned short*)ws;  ws += mixbytes;
  unsigned short* Wkb = (unsigned short*)ws; ws += wbytes;
  unsigned short* Wvb = (unsigned short*)ws; ws += wbytes;
  unsigned short* Wrb = (unsigned short*)ws; ws += wbytes;
  unsigned short* Wob = (unsigned short*)ws; ws += wbytes;
  unsigned short* kbuf = (unsigned short*)ws; ws += mixbytes;
  unsigned short* vbuf = (unsigned short*)ws; ws += mixbytes;
  unsigned short* rbuf = (unsigned short*)ws; ws += mixbytes;
  // states overlay the dead xk/xv regions (12.6 MB < 67 MB)
  char* so = (char*)xkb;
  float* Sa = (float*)so; so += nstate * 4;
  float* Sb = (float*)so; so += nstate * 4;
  float* Sp = (float*)so; so += nstate * 4;
  float* Ia = (float*)so; so += nstate * 4;
  float* Ib = (float*)so; so += nstate * 4;
  float* Ip = (float*)so; so += nstate * 4;

  dim3 blk(256);
  dim3 blk8(512);
  const int wkv_grid = (int)(nstate / 2 / 256);   // 1024

  mix3_castw_kernel<<<MIXGRID + CASTGRID, blk, 0, stream>>>(
      x, tmk, tmv, tmr, xkb, xvb, xrb,
      Wk, Wv, Wr, Wo, Wkb, Wvb, Wrb, Wob);
  gemm8_kvr<<<768, blk8, 0, stream>>>(xkb, xvb, xrb, Wkb, Wvb, Wrb,
                                      kbuf, vbuf, rbuf);

  wkv_phase1<<<wkv_grid, blk, 0, stream>>>(kbuf, vbuf, tdec, Sa, Sb, Sp);
  wkv_phase2<<<(BB * CC + 255) / 256, blk, 0, stream>>>(tdec, Sa, Sb, Sp, Ia, Ib, Ip);
  wkv_phase3<<<wkv_grid, blk, 0, stream>>>(kbuf, vbuf, rbuf, tdec, tfir,
                                           Ia, Ib, Ip, rbuf);  // in-place gate

  gemm8_one<<<256, blk8, 0, stream>>>(rbuf, Wob, (float*)d_out);
}

// Round 14
// 237.635 us; speedup vs baseline: 1.2058x; 1.0047x over previous
//
#include <hip/hip_runtime.h>

#define BB 8
#define TT 2048
#define CC 1024
#define WKV_L 32
#define WKV_NCH (TT / WKV_L)   // 64 chunks
#define WKV_LOG_NCH 6

typedef __bf16 bf16x8_t __attribute__((ext_vector_type(8)));
typedef float f32x4_t __attribute__((ext_vector_type(4)));
typedef unsigned short ushort8_t __attribute__((ext_vector_type(8)));

__device__ __forceinline__ unsigned short f2bf(float f) {
  unsigned u = __float_as_uint(f);
  u += 0x7fffu + ((u >> 16) & 1u);   // round-to-nearest-even
  return (unsigned short)(u >> 16);
}
__device__ __forceinline__ float bf2f(unsigned short s) {
  return __uint_as_float(((unsigned)s) << 16);
}

#define GLOAD16(gp, lp)                                                        \
  __builtin_amdgcn_global_load_lds(                                            \
      (const __attribute__((address_space(1))) void*)(gp),                     \
      (__attribute__((address_space(3))) void*)(lp), 16, 0, 0)

// ---- fused mix3 (grid-stride, proven) + weight casts --------------------
#define MIXGRID 2048
#define CASTGRID 256

__global__ __launch_bounds__(256) void mix3_castw_kernel(
    const float* __restrict__ x, const float* __restrict__ tmk,
    const float* __restrict__ tmv, const float* __restrict__ tmr,
    unsigned short* __restrict__ xk, unsigned short* __restrict__ xv,
    unsigned short* __restrict__ xr,
    const float* __restrict__ w0, const float* __restrict__ w1,
    const float* __restrict__ w2, const float* __restrict__ w3,
    unsigned short* __restrict__ o0, unsigned short* __restrict__ o1,
    unsigned short* __restrict__ o2, unsigned short* __restrict__ o3) {
  const int bid = blockIdx.x;
  const int tid = threadIdx.x;
  if (bid < MIXGRID) {
    const size_t total8 = (size_t)BB * TT * CC / 8;
    for (size_t i = (size_t)bid * 256 + tid; i < total8;
         i += (size_t)MIXGRID * 256) {
      size_t e = i * 8;
      int c = (int)(e & (CC - 1));
      int t = (int)((e >> 10) & (TT - 1));
      float4 xa = *(const float4*)(x + e);
      float4 xb = *(const float4*)(x + e + 4);
      float4 pa = make_float4(0.f, 0.f, 0.f, 0.f), pb = pa;
      if (t > 0) {
        pa = *(const float4*)(x + e - CC);
        pb = *(const float4*)(x + e - CC + 4);
      }
      float4 mka = *(const float4*)(tmk + c), mkb = *(const float4*)(tmk + c + 4);
      float4 mva = *(const float4*)(tmv + c), mvb = *(const float4*)(tmv + c + 4);
      float4 mra = *(const float4*)(tmr + c), mrb = *(const float4*)(tmr + c + 4);
      ushort8_t ok, ov, orr;
#define MIX1(dst, idx, xv_, pv_, m_) dst[idx] = f2bf(xv_ * m_ + pv_ * (1.f - m_));
      MIX1(ok, 0, xa.x, pa.x, mka.x) MIX1(ok, 1, xa.y, pa.y, mka.y)
      MIX1(ok, 2, xa.z, pa.z, mka.z) MIX1(ok, 3, xa.w, pa.w, mka.w)
      MIX1(ok, 4, xb.x, pb.x, mkb.x) MIX1(ok, 5, xb.y, pb.y, mkb.y)
      MIX1(ok, 6, xb.z, pb.z, mkb.z) MIX1(ok, 7, xb.w, pb.w, mkb.w)
      MIX1(ov, 0, xa.x, pa.x, mva.x) MIX1(ov, 1, xa.y, pa.y, mva.y)
      MIX1(ov, 2, xa.z, pa.z, mva.z) MIX1(ov, 3, xa.w, pa.w, mva.w)
      MIX1(ov, 4, xb.x, pb.x, mvb.x) MIX1(ov, 5, xb.y, pb.y, mvb.y)
      MIX1(ov, 6, xb.z, pb.z, mvb.z) MIX1(ov, 7, xb.w, pb.w, mvb.w)
      MIX1(orr, 0, xa.x, pa.x, mra.x) MIX1(orr, 1, xa.y, pa.y, mra.y)
      MIX1(orr, 2, xa.z, pa.z, mra.z) MIX1(orr, 3, xa.w, pa.w, mra.w)
      MIX1(orr, 4, xb.x, pb.x, mrb.x) MIX1(orr, 5, xb.y, pb.y, mrb.y)
      MIX1(orr, 6, xb.z, pb.z, mrb.z) MIX1(orr, 7, xb.w, pb.w, mrb.w)
#undef MIX1
      *(ushort8_t*)(xk + e) = ok;
      *(ushort8_t*)(xv + e) = ov;
      *(ushort8_t*)(xr + e) = orr;
    }
  } else {
    const int n4 = CC * CC / 4;   // per weight
    for (int i = (bid - MIXGRID) * 256 + tid; i < 4 * n4;
         i += CASTGRID * 256) {
      int sel = i / n4;
      int j = i - sel * n4;
      const float* w = sel == 0 ? w0 : sel == 1 ? w1 : sel == 2 ? w2 : w3;
      unsigned short* o = sel == 0 ? o0 : sel == 1 ? o1 : sel == 2 ? o2 : o3;
      float4 v = ((const float4*)w)[j];
      ushort4 u;
      u.x = f2bf(v.x); u.y = f2bf(v.y); u.z = f2bf(v.z); u.w = f2bf(v.w);
      ((ushort4*)o)[j] = u;
    }
  }
}

// ---- 256x256 8-phase GEMM, decoupled reads (R13 bugs FIXED) -------------
// Fix 1 (prologue): vmcnt(6) -> BARRIER -> reads (cross-wave publish).
// Fix 2 (epilogue): boundary-exact vmcnt via unroll-folded branches:
//   P0: t+1<NT8 ? {STG_B; vmcnt(8)} : vmcnt(0)    [retire B1(t)]
//   P3: t+2<NT8 ? {STG_A; vmcnt(8)} : t+1<NT8 ? vmcnt(2) : none
//   [retire A0/B0/A1(t+1) before their post-MFMA reads]
// Registers: aF single-buffered [4][2] (A-h0 dies at P1's MFMA before the
// refill; A-h1 dies at P3's MFMA before its refill); bF double [2][2][2]
// (B-h0 live P3(t-1)..P2(t) overlaps B-h1 live P0..P3). Same budget as R12.
// LDS WAR safety: every region's last ds_read is lgkm-forced before the
// consuming MFMA, which precedes >=1 barrier before any wave's same-region
// gload issue (checked per region/parity).
#define NT8 (CC / 64)   // 16 K-tiles

template <typename EPI>
__device__ __forceinline__ void gemm8_body(unsigned short* lds8,
                                           const unsigned short* __restrict__ A,
                                           const unsigned short* __restrict__ Bm,
                                           int tm, int tn, EPI epi) {
  const int tid = threadIdx.x;
  const int lane = tid & 63;
  const int wid = tid >> 6;
  const int wr = wid >> 2;   // 0..1
  const int wc = wid & 3;    // 0..3
  const int fr = lane & 15;
  const int fk = lane >> 4;  // 0..3

  const int srow = tid >> 3;                          // 0..63
  const int gcol = (((tid & 7) ^ (srow & 7)) << 3);   // pre-swizzled global col
  const unsigned short* Ag = A + (size_t)(tm * 256 + srow) * CC + gcol;
  const unsigned short* Bg = Bm + (size_t)(tn * 256 + srow) * CC + gcol;
  const int ldst = tid << 3;                          // linear LDS dest (elems)

  const int ab0 = (wr * 16 + fr) * 64;                // A base (elems, + parity)
  const int bb0 = 32768 + (wc * 16 + fr) * 64;        // B base
  const int sx0 = ((fk ^ (fr & 7)) << 3);             // read-side un-swizzle, kk=0
  const int sx1 = (((4 + fk) ^ (fr & 7)) << 3);       // kk=1

  bf16x8_t aF[4][2];      // single-buffered A half
  bf16x8_t bF[2][2][2];   // [half][j][kk]
  f32x4_t acc[8][4] = {};

#define STG_A(T, H)                                                            \
  {                                                                            \
    const unsigned short* g_ = Ag + (size_t)((H) * 128) * CC + (T) * 64;       \
    unsigned short* l_ = &lds8[(((T) & 1) << 14) + (H) * 8192 + ldst];         \
    GLOAD16(g_, l_);                                                           \
    GLOAD16(g_ + (size_t)64 * CC, l_ + 4096);                                  \
  }
#define STG_B(T, H)                                                            \
  {                                                                            \
    const unsigned short* g_ = Bg + (size_t)((H) * 128) * CC + (T) * 64;       \
    unsigned short* l_ = &lds8[32768 + (((T) & 1) << 14) + (H) * 8192 + ldst]; \
    GLOAD16(g_, l_);                                                           \
    GLOAD16(g_ + (size_t)64 * CC, l_ + 4096);                                  \
  }
#define LOADA(MH, AB)                                                          \
  _Pragma("unroll") for (int i_ = 0; i_ < 4; ++i_) {                           \
    aF[i_][0] = *(const bf16x8_t*)&lds8[(AB) + ((MH) * 4 + i_) * 2048 + sx0];  \
    aF[i_][1] = *(const bf16x8_t*)&lds8[(AB) + ((MH) * 4 + i_) * 2048 + sx1];  \
  }
#define LOADB(NH, BB2)                                                         \
  _Pragma("unroll") for (int j_ = 0; j_ < 2; ++j_) {                           \
    bF[NH][j_][0] = *(const bf16x8_t*)&lds8[(BB2) + ((NH) * 2 + j_) * 4096 + sx0]; \
    bF[NH][j_][1] = *(const bf16x8_t*)&lds8[(BB2) + ((NH) * 2 + j_) * 4096 + sx1]; \
  }
#define MFMAQ(MH, NH)                                                          \
  _Pragma("unroll") for (int i_ = 0; i_ < 4; ++i_)                             \
  _Pragma("unroll") for (int j_ = 0; j_ < 2; ++j_) {                           \
    acc[(MH) * 4 + i_][(NH) * 2 + j_] = __builtin_amdgcn_mfma_f32_16x16x32_bf16( \
        aF[i_][0], bF[NH][j_][0], acc[(MH) * 4 + i_][(NH) * 2 + j_], 0, 0, 0); \
    acc[(MH) * 4 + i_][(NH) * 2 + j_] = __builtin_amdgcn_mfma_f32_16x16x32_bf16( \
        aF[i_][1], bF[NH][j_][1], acc[(MH) * 4 + i_][(NH) * 2 + j_], 0, 0, 0); \
  }

  // prologue: tile0 (8 insts) + tile1 {A0,B0,A1} (6); vmcnt(6) lands tile0
  // for THIS wave; barrier publishes across waves; THEN read A-h0/B-h0(0).
  STG_A(0, 0) STG_B(0, 0) STG_A(0, 1) STG_B(0, 1)
  STG_A(1, 0) STG_B(1, 0) STG_A(1, 1)
  asm volatile("s_waitcnt vmcnt(6)" ::: "memory");
  __builtin_amdgcn_s_barrier();
  LOADA(0, ab0) LOADB(0, bb0)

#pragma unroll
  for (int t = 0; t < NT8; ++t) {
    const int pc = (t & 1) << 14;
    const int pn = ((t + 1) & 1) << 14;
    // ---- P0: MFMA(0,0); post-MFMA read bF1 <- B-h1(t)
    if (t + 1 < NT8) {
      STG_B(t + 1, 1)
      asm volatile("s_waitcnt vmcnt(8)" ::: "memory");   // retires B1(t)
    } else {
      asm volatile("s_waitcnt vmcnt(0)" ::: "memory");   // last tile: drain B1
    }
    __builtin_amdgcn_s_barrier();
    __builtin_amdgcn_s_setprio(1);
    MFMAQ(0, 0)
    __builtin_amdgcn_s_setprio(0);
    LOADB(1, bb0 + pc)
    __builtin_amdgcn_s_barrier();
    // ---- P1: MFMA(0,1); post-MFMA refill aF <- A-h1(t)
    if (t + 2 < NT8) { STG_A(t + 2, 0) }
    __builtin_amdgcn_s_barrier();
    __builtin_amdgcn_s_setprio(1);
    MFMAQ(0, 1)
    __builtin_amdgcn_s_setprio(0);
    LOADA(1, ab0 + pc)
    __builtin_amdgcn_s_barrier();
    // ---- P2: MFMA(1,0); no reads
    if (t + 2 < NT8) { STG_B(t + 2, 0) }
    __builtin_amdgcn_s_barrier();
    __builtin_amdgcn_s_setprio(1);
    MFMAQ(1, 0)
    __builtin_amdgcn_s_setprio(0);
    __builtin_amdgcn_s_barrier();
    // ---- P3: MFMA(1,1); post-MFMA refill aF/bF0 <- A-h0/B-h0(t+1)
    if (t + 2 < NT8) {
      STG_A(t + 2, 1)
      asm volatile("s_waitcnt vmcnt(8)" ::: "memory");   // retires A0/B0/A1(t+1)
    } else if (t + 1 < NT8) {
      asm volatile("s_waitcnt vmcnt(2)" ::: "memory");   // t=NT8-2: same retire
    }
    __builtin_amdgcn_s_barrier();
    __builtin_amdgcn_s_setprio(1);
    MFMAQ(1, 1)
    __builtin_amdgcn_s_setprio(0);
    if (t + 1 < NT8) { LOADA(0, ab0 + pn) LOADB(0, bb0 + pn) }
    __builtin_amdgcn_s_barrier();
  }

  // epilogue: C/D layout col=lane&15, row=fk*4+rg; frag (im,jn) at
  // rows wr*16+32*im, cols wc*16+64*jn (interleaved wave mapping)
#pragma unroll
  for (int im = 0; im < 8; ++im)
#pragma unroll
    for (int jn = 0; jn < 4; ++jn)
#pragma unroll
      for (int rg = 0; rg < 4; ++rg)
        epi((size_t)(tm * 256 + wr * 16 + im * 32 + (fk << 2) + rg) * CC +
                (size_t)(tn * 256 + wc * 16 + jn * 64 + fr),
            acc[im][jn][rg]);
#undef STG_A
#undef STG_B
#undef LOADA
#undef LOADB
#undef MFMAQ
}

// merged k/v/r projection: 768 blocks, XCD-swizzled, all outputs bf16
__global__ __launch_bounds__(512, 2) void gemm8_kvr(
    const unsigned short* __restrict__ xk, const unsigned short* __restrict__ xv,
    const unsigned short* __restrict__ xr, const unsigned short* __restrict__ Wk,
    const unsigned short* __restrict__ Wv, const unsigned short* __restrict__ Wr,
    unsigned short* __restrict__ kout, unsigned short* __restrict__ vout,
    unsigned short* __restrict__ rout) {
  __shared__ unsigned short lds8[65536];   // 128 KB
  int orig = blockIdx.x;
  int wg = (orig & 7) * 96 + (orig >> 3);
  int which = wg >> 8;        // 256 tiles per matrix
  int rr = wg & 255;
  int tm = rr >> 2;           // tn-fast within XCD chunk
  int tn = rr & 3;
  const unsigned short* A = which == 0 ? xk : which == 1 ? xv : xr;
  const unsigned short* Bm = which == 0 ? Wk : which == 1 ? Wv : Wr;
  unsigned short* o = which == 0 ? kout : which == 1 ? vout : rout;
  gemm8_body(lds8, A, Bm, tm, tn,
             [&](size_t off, float val) { o[off] = f2bf(val); });
}

// single GEMM (256 blocks, XCD-swizzled), fp32 out (final projection)
__global__ __launch_bounds__(512, 2) void gemm8_one(const unsigned short* __restrict__ A,
                         const unsigned short* __restrict__ Bm,
                         float* __restrict__ Cm) {
  __shared__ unsigned short lds8[65536];   // 128 KB
  int orig = blockIdx.x;
  int wg = (orig & 7) * 32 + (orig >> 3);
  int tm = wg >> 2;
  int tn = wg & 3;
  gemm8_body(lds8, A, Bm, tm, tn,
             [&](size_t off, float val) { Cm[off] = val; });
}

// ---- Chunk-parallel WKV scan, anchor-decay, 2 ch/thread, load pipeline ---
__global__ __launch_bounds__(256) void wkv_phase1(const unsigned short* __restrict__ k,
                           const unsigned short* __restrict__ v,
                           const float* __restrict__ wdec,
                           float* __restrict__ Sa, float* __restrict__ Sb,
                           float* __restrict__ Sp) {
  int idx = blockIdx.x * blockDim.x + threadIdx.x;  // (b*NCH + j)*(CC/2) + c2
  int c = (idx & (CC / 2 - 1)) << 1;
  int bj = idx >> 9;
  int j = bj & (WKV_NCH - 1);
  int b = bj >> WKV_LOG_NCH;
  float w0 = -__expf(wdec[c]), w1 = -__expf(wdec[c + 1]);
  size_t off = ((size_t)b * TT + (size_t)j * WKV_L) * CC + c;
  float aa0 = 0.f, bb0 = 0.f, pp0 = -1e38f;
  float aa1 = 0.f, bb1 = 0.f, pp1 = -1e38f;
  ushort2 kk = *(const ushort2*)(k + off);
  ushort2 vv = *(const ushort2*)(v + off);
  for (int t = 0; t < WKV_L; ++t) {
    size_t noff = off + ((t + 1 < WKV_L) ? CC : 0);
    ushort2 nk = *(const ushort2*)(k + noff);
    ushort2 nv = *(const ushort2*)(v + noff);
    float k0 = bf2f(kk.x), k1 = bf2f(kk.y);
    float v0 = bf2f(vv.x), v1 = bf2f(vv.y);
    pp0 += w0; pp1 += w1;
    float d0 = k0 - pp0, d1 = k1 - pp1;
    if (d0 > 8.f) { float s = __expf(-d0); aa0 *= s; bb0 *= s; pp0 = k0; d0 = 0.f; }
    if (d1 > 8.f) { float s = __expf(-d1); aa1 *= s; bb1 *= s; pp1 = k1; d1 = 0.f; }
    float E0 = __expf(d0), E1 = __expf(d1);
    aa0 = fmaf(E0, v0, aa0); bb0 += E0;
    aa1 = fmaf(E1, v1, aa1); bb1 += E1;
    kk = nk; vv = nv; off = noff;
  }
  size_t s = (size_t)bj * CC + c;
  *(float2*)(Sa + s) = make_float2(aa0, aa1);
  *(float2*)(Sb + s) = make_float2(bb0, bb1);
  *(float2*)(Sp + s) = make_float2(pp0, pp1);
}

// serial scan over chunk summaries -> incoming state per chunk
__global__ __launch_bounds__(256) void wkv_phase2(const float* __restrict__ wdec,
                           const float* __restrict__ Sa, const float* __restrict__ Sb,
                           const float* __restrict__ Sp,
                           float* __restrict__ Ia, float* __restrict__ Ib,
                           float* __restrict__ Ip) {
  int idx = blockIdx.x * blockDim.x + threadIdx.x;  // b*CC + c
  if (idx >= BB * CC) return;
  int c = idx & (CC - 1);
  int b = idx >> 10;
  float wL = -__expf(wdec[c]) * (float)WKV_L;
  float aa = 0.f, bb = 0.f, pp = -1e38f;
  for (int j = 0; j < WKV_NCH; ++j) {
    size_t s = (size_t)(b * WKV_NCH + j) * CC + c;
    Ia[s] = aa; Ib[s] = bb; Ip[s] = pp;
    float pd = pp + wL;
    float ps = Sp[s];
    float q = fmaxf(pd, ps);
    float e1 = __expf(pd - q);
    float e2 = __expf(ps - q);
    aa = fmaf(e1, aa, e2 * Sa[s]);
    bb = fmaf(e1, bb, e2 * Sb[s]);
    pp = q;
  }
}

// phase3: anchor-decay replay + fused sigmoid(r)*y, 2 ch/thread, in-place,
// with t+1 load prefetch.
__global__ __launch_bounds__(256) void wkv_phase3(const unsigned short* __restrict__ k,
                           const unsigned short* __restrict__ v,
                           const unsigned short* r,
                           const float* __restrict__ wdec,
                           const float* __restrict__ u,
                           const float* __restrict__ Ia, const float* __restrict__ Ib,
                           const float* __restrict__ Ip,
                           unsigned short* out) {
  int idx = blockIdx.x * blockDim.x + threadIdx.x;
  int c = (idx & (CC / 2 - 1)) << 1;
  int bj = idx >> 9;
  int j = bj & (WKV_NCH - 1);
  int b = bj >> WKV_LOG_NCH;
  float w0 = -__expf(wdec[c]), w1 = -__expf(wdec[c + 1]);
  float u0 = u[c], u1 = u[c + 1];
  size_t st = (size_t)bj * CC + c;
  float2 a2 = *(const float2*)(Ia + st);
  float2 b2 = *(const float2*)(Ib + st);
  float2 p2 = *(const float2*)(Ip + st);
  float aa0 = a2.x, bb0 = b2.x, pp0 = p2.x;
  float aa1 = a2.y, bb1 = b2.y, pp1 = p2.y;
  size_t off = ((size_t)b * TT + (size_t)j * WKV_L) * CC + c;
  ushort2 kk = *(const ushort2*)(k + off);
  ushort2 vv = *(const ushort2*)(v + off);
  ushort2 rr2 = *(const ushort2*)(r + off);
  for (int t = 0; t < WKV_L; ++t) {
    size_t noff = off + ((t + 1 < WKV_L) ? CC : 0);
    ushort2 nk = *(const ushort2*)(k + noff);
    ushort2 nv = *(const ushort2*)(v + noff);
    ushort2 nr = *(const ushort2*)(r + noff);
    float k0 = bf2f(kk.x), k1 = bf2f(kk.y);
    float v0 = bf2f(vv.x), v1 = bf2f(vv.y);
    // y from pre-decay state
    float dy0 = fminf(u0 + k0 - pp0, 60.f);
    float dy1 = fminf(u1 + k1 - pp1, 60.f);
    float Eu0 = __expf(dy0), Eu1 = __expf(dy1);
    float y0 = fmaf(Eu0, v0, aa0) / (bb0 + Eu0);
    float y1 = fmaf(Eu1, v1, aa1) / (bb1 + Eu1);
    float sr0 = 1.f / (1.f + __expf(-bf2f(rr2.x)));
    float sr1 = 1.f / (1.f + __expf(-bf2f(rr2.y)));
    ushort2 o;
    o.x = f2bf(sr0 * y0);
    o.y = f2bf(sr1 * y1);
    *(ushort2*)(out + off) = o;
    // decay + rare renorm + accumulate
    pp0 += w0; pp1 += w1;
    float d0 = k0 - pp0, d1 = k1 - pp1;
    if (d0 > 8.f) { float s = __expf(-d0); aa0 *= s; bb0 *= s; pp0 = k0; d0 = 0.f; }
    if (d1 > 8.f) { float s = __expf(-d1); aa1 *= s; bb1 *= s; pp1 = k1; d1 = 0.f; }
    float E0 = __expf(d0), E1 = __expf(d1);
    aa0 = fmaf(E0, v0, aa0); bb0 += E0;
    aa1 = fmaf(E1, v1, aa1); bb1 += E1;
    kk = nk; vv = nv; rr2 = nr; off = noff;
  }
}

extern "C" void kernel_launch(void* const* d_in, const int* in_sizes, int n_in,
                              void* d_out, int out_size, void* d_ws, size_t ws_size,
                              hipStream_t stream) {
  const float* x    = (const float*)d_in[0];
  const float* tdec = (const float*)d_in[1];
  const float* tfir = (const float*)d_in[2];
  const float* tmk  = (const float*)d_in[3];
  const float* tmv  = (const float*)d_in[4];
  const float* tmr  = (const float*)d_in[5];
  const float* Wk   = (const float*)d_in[6];
  const float* Wv   = (const float*)d_in[7];
  const float* Wr   = (const float*)d_in[8];
  const float* Wo   = (const float*)d_in[9];

  const size_t M = (size_t)BB * TT;     // 16384
  const size_t mixbytes = M * CC * 2;   // 33.5 MB
  const size_t wbytes = (size_t)CC * CC * 2;
  const size_t nstate = (size_t)BB * WKV_NCH * CC;   // 512K

  // Layout (~209 MB peak, proven fit):
  char* ws = (char*)d_ws;
  unsigned short* xkb = (unsigned short*)ws;  ws += mixbytes;
  unsigned short* xvb = (unsigned short*)ws;  ws += mixbytes;
  unsigned short* xrb = (unsigned short*)ws;  ws += mixbytes;
  unsigned short* Wkb = (unsigned short*)ws; ws += wbytes;
  unsigned short* Wvb = (unsigned short*)ws; ws += wbytes;
  unsigned short* Wrb = (unsigned short*)ws; ws += wbytes;
  unsigned short* Wob = (unsigned short*)ws; ws += wbytes;
  unsigned short* kbuf = (unsigned short*)ws; ws += mixbytes;
  unsigned short* vbuf = (unsigned short*)ws; ws += mixbytes;
  unsigned short* rbuf = (unsigned short*)ws; ws += mixbytes;
  // states overlay the dead xk/xv regions (12.6 MB < 67 MB)
  char* so = (char*)xkb;
  float* Sa = (float*)so; so += nstate * 4;
  float* Sb = (float*)so; so += nstate * 4;
  float* Sp = (float*)so; so += nstate * 4;
  float* Ia = (float*)so; so += nstate * 4;
  float* Ib = (float*)so; so += nstate * 4;
  float* Ip = (float*)so; so += nstate * 4;

  dim3 blk(256);
  dim3 blk8(512);
  const int wkv_grid = (int)(nstate / 2 / 256);   // 1024

  mix3_castw_kernel<<<MIXGRID + CASTGRID, blk, 0, stream>>>(
      x, tmk, tmv, tmr, xkb, xvb, xrb,
      Wk, Wv, Wr, Wo, Wkb, Wvb, Wrb, Wob);
  gemm8_kvr<<<768, blk8, 0, stream>>>(xkb, xvb, xrb, Wkb, Wvb, Wrb,
                                      kbuf, vbuf, rbuf);

  wkv_phase1<<<wkv_grid, blk, 0, stream>>>(kbuf, vbuf, tdec, Sa, Sb, Sp);
  wkv_phase2<<<(BB * CC + 255) / 256, blk, 0, stream>>>(tdec, Sa, Sb, Sp, Ia, Ib, Ip);
  wkv_phase3<<<wkv_grid, blk, 0, stream>>>(kbuf, vbuf, rbuf, tdec, tfir,
                                           Ia, Ib, Ip, rbuf);  // in-place gate

  gemm8_one<<<256, blk8, 0, stream>>>(rbuf, Wob, (float*)d_out);
}

// Round 15
// 236.340 us; speedup vs baseline: 1.2124x; 1.0055x over previous
//
#include <hip/hip_runtime.h>

#define BB 8
#define TT 2048
#define CC 1024
#define WKV_L 32
#define WKV_NCH (TT / WKV_L)   // 64 chunks
#define WKV_LOG_NCH 6

typedef __bf16 bf16x8_t __attribute__((ext_vector_type(8)));
typedef float f32x4_t __attribute__((ext_vector_type(4)));
typedef unsigned short ushort8_t __attribute__((ext_vector_type(8)));

__device__ __forceinline__ unsigned short f2bf(float f) {
  unsigned u = __float_as_uint(f);
  u += 0x7fffu + ((u >> 16) & 1u);   // round-to-nearest-even
  return (unsigned short)(u >> 16);
}
__device__ __forceinline__ float bf2f(unsigned short s) {
  return __uint_as_float(((unsigned)s) << 16);
}

#define GLOAD16(gp, lp)                                                        \
  __builtin_amdgcn_global_load_lds(                                            \
      (const __attribute__((address_space(1))) void*)(gp),                     \
      (__attribute__((address_space(3))) void*)(lp), 16, 0, 0)

// ---- fused mix3 (grid-stride, proven) + weight casts --------------------
#define MIXGRID 2048
#define CASTGRID 256

__global__ __launch_bounds__(256) void mix3_castw_kernel(
    const float* __restrict__ x, const float* __restrict__ tmk,
    const float* __restrict__ tmv, const float* __restrict__ tmr,
    unsigned short* __restrict__ xk, unsigned short* __restrict__ xv,
    unsigned short* __restrict__ xr,
    const float* __restrict__ w0, const float* __restrict__ w1,
    const float* __restrict__ w2, const float* __restrict__ w3,
    unsigned short* __restrict__ o0, unsigned short* __restrict__ o1,
    unsigned short* __restrict__ o2, unsigned short* __restrict__ o3) {
  const int bid = blockIdx.x;
  const int tid = threadIdx.x;
  if (bid < MIXGRID) {
    const size_t total8 = (size_t)BB * TT * CC / 8;
    for (size_t i = (size_t)bid * 256 + tid; i < total8;
         i += (size_t)MIXGRID * 256) {
      size_t e = i * 8;
      int c = (int)(e & (CC - 1));
      int t = (int)((e >> 10) & (TT - 1));
      float4 xa = *(const float4*)(x + e);
      float4 xb = *(const float4*)(x + e + 4);
      float4 pa = make_float4(0.f, 0.f, 0.f, 0.f), pb = pa;
      if (t > 0) {
        pa = *(const float4*)(x + e - CC);
        pb = *(const float4*)(x + e - CC + 4);
      }
      float4 mka = *(const float4*)(tmk + c), mkb = *(const float4*)(tmk + c + 4);
      float4 mva = *(const float4*)(tmv + c), mvb = *(const float4*)(tmv + c + 4);
      float4 mra = *(const float4*)(tmr + c), mrb = *(const float4*)(tmr + c + 4);
      ushort8_t ok, ov, orr;
#define MIX1(dst, idx, xv_, pv_, m_) dst[idx] = f2bf(xv_ * m_ + pv_ * (1.f - m_));
      MIX1(ok, 0, xa.x, pa.x, mka.x) MIX1(ok, 1, xa.y, pa.y, mka.y)
      MIX1(ok, 2, xa.z, pa.z, mka.z) MIX1(ok, 3, xa.w, pa.w, mka.w)
      MIX1(ok, 4, xb.x, pb.x, mkb.x) MIX1(ok, 5, xb.y, pb.y, mkb.y)
      MIX1(ok, 6, xb.z, pb.z, mkb.z) MIX1(ok, 7, xb.w, pb.w, mkb.w)
      MIX1(ov, 0, xa.x, pa.x, mva.x) MIX1(ov, 1, xa.y, pa.y, mva.y)
      MIX1(ov, 2, xa.z, pa.z, mva.z) MIX1(ov, 3, xa.w, pa.w, mva.w)
      MIX1(ov, 4, xb.x, pb.x, mvb.x) MIX1(ov, 5, xb.y, pb.y, mvb.y)
      MIX1(ov, 6, xb.z, pb.z, mvb.z) MIX1(ov, 7, xb.w, pb.w, mvb.w)
      MIX1(orr, 0, xa.x, pa.x, mra.x) MIX1(orr, 1, xa.y, pa.y, mra.y)
      MIX1(orr, 2, xa.z, pa.z, mra.z) MIX1(orr, 3, xa.w, pa.w, mra.w)
      MIX1(orr, 4, xb.x, pb.x, mrb.x) MIX1(orr, 5, xb.y, pb.y, mrb.y)
      MIX1(orr, 6, xb.z, pb.z, mrb.z) MIX1(orr, 7, xb.w, pb.w, mrb.w)
#undef MIX1
      *(ushort8_t*)(xk + e) = ok;
      *(ushort8_t*)(xv + e) = ov;
      *(ushort8_t*)(xr + e) = orr;
    }
  } else {
    const int n4 = CC * CC / 4;   // per weight
    for (int i = (bid - MIXGRID) * 256 + tid; i < 4 * n4;
         i += CASTGRID * 256) {
      int sel = i / n4;
      int j = i - sel * n4;
      const float* w = sel == 0 ? w0 : sel == 1 ? w1 : sel == 2 ? w2 : w3;
      unsigned short* o = sel == 0 ? o0 : sel == 1 ? o1 : sel == 2 ? o2 : o3;
      float4 v = ((const float4*)w)[j];
      ushort4 u;
      u.x = f2bf(v.x); u.y = f2bf(v.y); u.z = f2bf(v.z); u.w = f2bf(v.w);
      ((ushort4*)o)[j] = u;
    }
  }
}

// ---- 256x256 GEMM, 4 barriers/K-tile ------------------------------------
// Phase = [MFMA -> post-MFMA ds_reads -> guarded STG -> (vmcnt) -> barrier].
// Uniform 2-tile-ahead stream: {A0,B0,A1,B1}(t+2) issued one per phase.
// vmcnt induction (insts, 2 per stage): entering P0(t)=8 (tile t+1 complete);
// P2: 14 -> vmcnt(8) retires A0/B0/A1(t+1), publish at P2 bar for P3 reads;
// P3: 10 -> vmcnt(8) retires B1(t+1), publish for P0(t+1).
// Boundaries: t=NT8-2 -> vmcnt(4)@P2, vmcnt(0)@P3; t=NT8-1 -> none.
// Liveness (all single-buffered, 120 VGPR): aF0 read P3(t-1), used P0/P1,
// refill P3(t); aF1 read P1, used P2/P3; bF0 read P3(t-1), used P0/P2,
// refill P3(t); bF1 read P0, used P1/P3, refill P0(t+1).
// WAR windows all have >=1 barrier + 16-MFMA cluster + ~400cy gload-write
// latency slack between read-issue and cross-wave write-land.
#define NT8 (CC / 64)   // 16 K-tiles

template <typename EPI>
__device__ __forceinline__ void gemm8_body(unsigned short* lds8,
                                           const unsigned short* __restrict__ A,
                                           const unsigned short* __restrict__ Bm,
                                           int tm, int tn, EPI epi) {
  const int tid = threadIdx.x;
  const int lane = tid & 63;
  const int wid = tid >> 6;
  const int wr = wid >> 2;   // 0..1
  const int wc = wid & 3;    // 0..3
  const int fr = lane & 15;
  const int fk = lane >> 4;  // 0..3

  const int srow = tid >> 3;                          // 0..63
  const int gcol = (((tid & 7) ^ (srow & 7)) << 3);   // pre-swizzled global col
  const unsigned short* Ag = A + (size_t)(tm * 256 + srow) * CC + gcol;
  const unsigned short* Bg = Bm + (size_t)(tn * 256 + srow) * CC + gcol;
  const int ldst = tid << 3;                          // linear LDS dest (elems)

  const int ab0 = (wr * 16 + fr) * 64;                // A base (elems, + parity)
  const int bb0 = 32768 + (wc * 16 + fr) * 64;        // B base
  const int sx0 = ((fk ^ (fr & 7)) << 3);             // read-side un-swizzle, kk=0
  const int sx1 = (((4 + fk) ^ (fr & 7)) << 3);       // kk=1

  bf16x8_t aF[4][2];      // single-buffered A half
  bf16x8_t bF[2][2][2];   // [half][j][kk], each half single-buffered
  f32x4_t acc[8][4] = {};

#define STG_A(T, H)                                                            \
  {                                                                            \
    const unsigned short* g_ = Ag + (size_t)((H) * 128) * CC + (T) * 64;       \
    unsigned short* l_ = &lds8[(((T) & 1) << 14) + (H) * 8192 + ldst];         \
    GLOAD16(g_, l_);                                                           \
    GLOAD16(g_ + (size_t)64 * CC, l_ + 4096);                                  \
  }
#define STG_B(T, H)                                                            \
  {                                                                            \
    const unsigned short* g_ = Bg + (size_t)((H) * 128) * CC + (T) * 64;       \
    unsigned short* l_ = &lds8[32768 + (((T) & 1) << 14) + (H) * 8192 + ldst]; \
    GLOAD16(g_, l_);                                                           \
    GLOAD16(g_ + (size_t)64 * CC, l_ + 4096);                                  \
  }
#define LOADA(MH, AB)                                                          \
  _Pragma("unroll") for (int i_ = 0; i_ < 4; ++i_) {                           \
    aF[i_][0] = *(const bf16x8_t*)&lds8[(AB) + ((MH) * 4 + i_) * 2048 + sx0];  \
    aF[i_][1] = *(const bf16x8_t*)&lds8[(AB) + ((MH) * 4 + i_) * 2048 + sx1];  \
  }
#define LOADB(NH, BB2)                                                         \
  _Pragma("unroll") for (int j_ = 0; j_ < 2; ++j_) {                           \
    bF[NH][j_][0] = *(const bf16x8_t*)&lds8[(BB2) + ((NH) * 2 + j_) * 4096 + sx0]; \
    bF[NH][j_][1] = *(const bf16x8_t*)&lds8[(BB2) + ((NH) * 2 + j_) * 4096 + sx1]; \
  }
#define MFMAQ(MH, NH)                                                          \
  _Pragma("unroll") for (int i_ = 0; i_ < 4; ++i_)                             \
  _Pragma("unroll") for (int j_ = 0; j_ < 2; ++j_) {                           \
    acc[(MH) * 4 + i_][(NH) * 2 + j_] = __builtin_amdgcn_mfma_f32_16x16x32_bf16( \
        aF[i_][0], bF[NH][j_][0], acc[(MH) * 4 + i_][(NH) * 2 + j_], 0, 0, 0); \
    acc[(MH) * 4 + i_][(NH) * 2 + j_] = __builtin_amdgcn_mfma_f32_16x16x32_bf16( \
        aF[i_][1], bF[NH][j_][1], acc[(MH) * 4 + i_][(NH) * 2 + j_], 0, 0, 0); \
  }

  // prologue: tiles 0 AND 1 fully staged (16 insts); vmcnt(8) lands tile0;
  // barrier publishes; THEN pre-read aF0/bF0 of tile0.
  STG_A(0, 0) STG_B(0, 0) STG_A(0, 1) STG_B(0, 1)
  STG_A(1, 0) STG_B(1, 0) STG_A(1, 1) STG_B(1, 1)
  asm volatile("s_waitcnt vmcnt(8)" ::: "memory");
  __builtin_amdgcn_s_barrier();
  LOADA(0, ab0) LOADB(0, bb0)

#pragma unroll
  for (int t = 0; t < NT8; ++t) {
    const int pc = (t & 1) << 14;
    const int pn = ((t + 1) & 1) << 14;
    // ---- P0: MFMA(0,0); read bF1(t); stage A0(t+2)
    __builtin_amdgcn_s_setprio(1);
    MFMAQ(0, 0)
    __builtin_amdgcn_s_setprio(0);
    LOADB(1, bb0 + pc)
    if (t + 2 < NT8) { STG_A(t + 2, 0) }
    __builtin_amdgcn_s_barrier();
    // ---- P1: MFMA(0,1); read aF1(t); stage B0(t+2)
    __builtin_amdgcn_s_setprio(1);
    MFMAQ(0, 1)
    __builtin_amdgcn_s_setprio(0);
    LOADA(1, ab0 + pc)
    if (t + 2 < NT8) { STG_B(t + 2, 0) }
    __builtin_amdgcn_s_barrier();
    // ---- P2: MFMA(1,0); stage A1(t+2); retire A0/B0/A1(t+1)
    __builtin_amdgcn_s_setprio(1);
    MFMAQ(1, 0)
    __builtin_amdgcn_s_setprio(0);
    if (t + 2 < NT8) {
      STG_A(t + 2, 1)
      asm volatile("s_waitcnt vmcnt(8)" ::: "memory");
    } else if (t + 1 < NT8) {
      asm volatile("s_waitcnt vmcnt(4)" ::: "memory");
    }
    __builtin_amdgcn_s_barrier();
    // ---- P3: MFMA(1,1); read aF0/bF0(t+1); stage B1(t+2); retire B1(t+1)
    __builtin_amdgcn_s_setprio(1);
    MFMAQ(1, 1)
    __builtin_amdgcn_s_setprio(0);
    if (t + 1 < NT8) { LOADA(0, ab0 + pn) LOADB(0, bb0 + pn) }
    if (t + 2 < NT8) {
      STG_B(t + 2, 1)
      asm volatile("s_waitcnt vmcnt(8)" ::: "memory");
    } else if (t + 1 < NT8) {
      asm volatile("s_waitcnt vmcnt(0)" ::: "memory");
    }
    __builtin_amdgcn_s_barrier();
  }

  // epilogue: C/D layout col=lane&15, row=fk*4+rg; frag (im,jn) at
  // rows wr*16+32*im, cols wc*16+64*jn (interleaved wave mapping)
#pragma unroll
  for (int im = 0; im < 8; ++im)
#pragma unroll
    for (int jn = 0; jn < 4; ++jn)
#pragma unroll
      for (int rg = 0; rg < 4; ++rg)
        epi((size_t)(tm * 256 + wr * 16 + im * 32 + (fk << 2) + rg) * CC +
                (size_t)(tn * 256 + wc * 16 + jn * 64 + fr),
            acc[im][jn][rg]);
#undef STG_A
#undef STG_B
#undef LOADA
#undef LOADB
#undef MFMAQ
}

// merged k/v/r projection: 768 blocks, XCD-swizzled, all outputs bf16
__global__ __launch_bounds__(512, 2) void gemm8_kvr(
    const unsigned short* __restrict__ xk, const unsigned short* __restrict__ xv,
    const unsigned short* __restrict__ xr, const unsigned short* __restrict__ Wk,
    const unsigned short* __restrict__ Wv, const unsigned short* __restrict__ Wr,
    unsigned short* __restrict__ kout, unsigned short* __restrict__ vout,
    unsigned short* __restrict__ rout) {
  __shared__ unsigned short lds8[65536];   // 128 KB
  int orig = blockIdx.x;
  int wg = (orig & 7) * 96 + (orig >> 3);
  int which = wg >> 8;        // 256 tiles per matrix
  int rr = wg & 255;
  int tm = rr >> 2;           // tn-fast within XCD chunk
  int tn = rr & 3;
  const unsigned short* A = which == 0 ? xk : which == 1 ? xv : xr;
  const unsigned short* Bm = which == 0 ? Wk : which == 1 ? Wv : Wr;
  unsigned short* o = which == 0 ? kout : which == 1 ? vout : rout;
  gemm8_body(lds8, A, Bm, tm, tn,
             [&](size_t off, float val) { o[off] = f2bf(val); });
}

// single GEMM (256 blocks, XCD-swizzled), fp32 out (final projection)
__global__ __launch_bounds__(512, 2) void gemm8_one(const unsigned short* __restrict__ A,
                         const unsigned short* __restrict__ Bm,
                         float* __restrict__ Cm) {
  __shared__ unsigned short lds8[65536];   // 128 KB
  int orig = blockIdx.x;
  int wg = (orig & 7) * 32 + (orig >> 3);
  int tm = wg >> 2;
  int tn = wg & 3;
  gemm8_body(lds8, A, Bm, tm, tn,
             [&](size_t off, float val) { Cm[off] = val; });
}

// ---- Chunk-parallel WKV scan, anchor-decay, 4 ch/thread, load pipeline ---
__global__ __launch_bounds__(256) void wkv_phase1(const unsigned short* __restrict__ k,
                           const unsigned short* __restrict__ v,
                           const float* __restrict__ wdec,
                           float* __restrict__ Sa, float* __restrict__ Sb,
                           float* __restrict__ Sp) {
  int idx = blockIdx.x * blockDim.x + threadIdx.x;  // (b*NCH + j)*(CC/4) + c4
  int c = (idx & (CC / 4 - 1)) << 2;
  int bj = idx >> 8;
  int j = bj & (WKV_NCH - 1);
  int b = bj >> WKV_LOG_NCH;
  float w[4], aa[4], bb[4], pp[4];
#pragma unroll
  for (int q = 0; q < 4; ++q) {
    w[q] = -__expf(wdec[c + q]);
    aa[q] = 0.f; bb[q] = 0.f; pp[q] = -1e38f;
  }
  size_t off = ((size_t)b * TT + (size_t)j * WKV_L) * CC + c;
  ushort4 kk = *(const ushort4*)(k + off);
  ushort4 vv = *(const ushort4*)(v + off);
  for (int t = 0; t < WKV_L; ++t) {
    size_t noff = off + ((t + 1 < WKV_L) ? CC : 0);
    ushort4 nk = *(const ushort4*)(k + noff);
    ushort4 nv = *(const ushort4*)(v + noff);
    const unsigned short* kp = (const unsigned short*)&kk;
    const unsigned short* vp = (const unsigned short*)&vv;
#pragma unroll
    for (int q = 0; q < 4; ++q) {
      float kt = bf2f(kp[q]);
      float vt = bf2f(vp[q]);
      pp[q] += w[q];
      float d = kt - pp[q];
      if (d > 8.f) { float s = __expf(-d); aa[q] *= s; bb[q] *= s; pp[q] = kt; d = 0.f; }
      float E = __expf(d);
      aa[q] = fmaf(E, vt, aa[q]); bb[q] += E;
    }
    kk = nk; vv = nv; off = noff;
  }
  size_t s = (size_t)bj * CC + c;
  *(float4*)(Sa + s) = make_float4(aa[0], aa[1], aa[2], aa[3]);
  *(float4*)(Sb + s) = make_float4(bb[0], bb[1], bb[2], bb[3]);
  *(float4*)(Sp + s) = make_float4(pp[0], pp[1], pp[2], pp[3]);
}

// serial scan over chunk summaries -> incoming state per chunk
__global__ __launch_bounds__(256) void wkv_phase2(const float* __restrict__ wdec,
                           const float* __restrict__ Sa, const float* __restrict__ Sb,
                           const float* __restrict__ Sp,
                           float* __restrict__ Ia, float* __restrict__ Ib,
                           float* __restrict__ Ip) {
  int idx = blockIdx.x * blockDim.x + threadIdx.x;  // b*CC + c
  if (idx >= BB * CC) return;
  int c = idx & (CC - 1);
  int b = idx >> 10;
  float wL = -__expf(wdec[c]) * (float)WKV_L;
  float aa = 0.f, bb = 0.f, pp = -1e38f;
  for (int j = 0; j < WKV_NCH; ++j) {
    size_t s = (size_t)(b * WKV_NCH + j) * CC + c;
    Ia[s] = aa; Ib[s] = bb; Ip[s] = pp;
    float pd = pp + wL;
    float ps = Sp[s];
    float q = fmaxf(pd, ps);
    float e1 = __expf(pd - q);
    float e2 = __expf(ps - q);
    aa = fmaf(e1, aa, e2 * Sa[s]);
    bb = fmaf(e1, bb, e2 * Sb[s]);
    pp = q;
  }
}

// phase3: anchor-decay replay + fused sigmoid(r)*y, 4 ch/thread, in-place,
// with t+1 load prefetch.
__global__ __launch_bounds__(256) void wkv_phase3(const unsigned short* __restrict__ k,
                           const unsigned short* __restrict__ v,
                           const unsigned short* r,
                           const float* __restrict__ wdec,
                           const float* __restrict__ u,
                           const float* __restrict__ Ia, const float* __restrict__ Ib,
                           const float* __restrict__ Ip,
                           unsigned short* out) {
  int idx = blockIdx.x * blockDim.x + threadIdx.x;
  int c = (idx & (CC / 4 - 1)) << 2;
  int bj = idx >> 8;
  int j = bj & (WKV_NCH - 1);
  int b = bj >> WKV_LOG_NCH;
  float w[4], uu[4], aa[4], bb[4], pp[4];
  size_t st = (size_t)bj * CC + c;
  float4 a4 = *(const float4*)(Ia + st);
  float4 b4 = *(const float4*)(Ib + st);
  float4 p4 = *(const float4*)(Ip + st);
  aa[0] = a4.x; aa[1] = a4.y; aa[2] = a4.z; aa[3] = a4.w;
  bb[0] = b4.x; bb[1] = b4.y; bb[2] = b4.z; bb[3] = b4.w;
  pp[0] = p4.x; pp[1] = p4.y; pp[2] = p4.z; pp[3] = p4.w;
#pragma unroll
  for (int q = 0; q < 4; ++q) {
    w[q] = -__expf(wdec[c + q]);
    uu[q] = u[c + q];
  }
  size_t off = ((size_t)b * TT + (size_t)j * WKV_L) * CC + c;
  ushort4 kk = *(const ushort4*)(k + off);
  ushort4 vv = *(const ushort4*)(v + off);
  ushort4 rr4 = *(const ushort4*)(r + off);
  for (int t = 0; t < WKV_L; ++t) {
    size_t noff = off + ((t + 1 < WKV_L) ? CC : 0);
    ushort4 nk = *(const ushort4*)(k + noff);
    ushort4 nv = *(const ushort4*)(v + noff);
    ushort4 nr = *(const ushort4*)(r + noff);
    const unsigned short* kp = (const unsigned short*)&kk;
    const unsigned short* vp = (const unsigned short*)&vv;
    const unsigned short* rp = (const unsigned short*)&rr4;
    ushort4 o4;
    unsigned short* op = (unsigned short*)&o4;
#pragma unroll
    for (int q = 0; q < 4; ++q) {
      float kt = bf2f(kp[q]);
      float vt = bf2f(vp[q]);
      float dy = fminf(uu[q] + kt - pp[q], 60.f);
      float Eu = __expf(dy);
      float y = fmaf(Eu, vt, aa[q]) / (bb[q] + Eu);
      float sr = 1.f / (1.f + __expf(-bf2f(rp[q])));
      op[q] = f2bf(sr * y);
      pp[q] += w[q];
      float d = kt - pp[q];
      if (d > 8.f) { float s = __expf(-d); aa[q] *= s; bb[q] *= s; pp[q] = kt; d = 0.f; }
      float E = __expf(d);
      aa[q] = fmaf(E, vt, aa[q]); bb[q] += E;
    }
    *(ushort4*)(out + off) = o4;
    kk = nk; vv = nv; rr4 = nr; off = noff;
  }
}

extern "C" void kernel_launch(void* const* d_in, const int* in_sizes, int n_in,
                              void* d_out, int out_size, void* d_ws, size_t ws_size,
                              hipStream_t stream) {
  const float* x    = (const float*)d_in[0];
  const float* tdec = (const float*)d_in[1];
  const float* tfir = (const float*)d_in[2];
  const float* tmk  = (const float*)d_in[3];
  const float* tmv  = (const float*)d_in[4];
  const float* tmr  = (const float*)d_in[5];
  const float* Wk   = (const float*)d_in[6];
  const float* Wv   = (const float*)d_in[7];
  const float* Wr   = (const float*)d_in[8];
  const float* Wo   = (const float*)d_in[9];

  const size_t M = (size_t)BB * TT;     // 16384
  const size_t mixbytes = M * CC * 2;   // 33.5 MB
  const size_t wbytes = (size_t)CC * CC * 2;
  const size_t nstate = (size_t)BB * WKV_NCH * CC;   // 512K

  // Layout (~209 MB peak, proven fit):
  char* ws = (char*)d_ws;
  unsigned short* xkb = (unsigned short*)ws;  ws += mixbytes;
  unsigned short* xvb = (unsigned short*)ws;  ws += mixbytes;
  unsigned short* xrb = (unsigned short*)ws;  ws += mixbytes;
  unsigned short* Wkb = (unsigned short*)ws; ws += wbytes;
  unsigned short* Wvb = (unsigned short*)ws; ws += wbytes;
  unsigned short* Wrb = (unsigned short*)ws; ws += wbytes;
  unsigned short* Wob = (unsigned short*)ws; ws += wbytes;
  unsigned short* kbuf = (unsigned short*)ws; ws += mixbytes;
  unsigned short* vbuf = (unsigned short*)ws; ws += mixbytes;
  unsigned short* rbuf = (unsigned short*)ws; ws += mixbytes;
  // states overlay the dead xk/xv regions (12.6 MB < 67 MB)
  char* so = (char*)xkb;
  float* Sa = (float*)so; so += nstate * 4;
  float* Sb = (float*)so; so += nstate * 4;
  float* Sp = (float*)so; so += nstate * 4;
  float* Ia = (float*)so; so += nstate * 4;
  float* Ib = (float*)so; so += nstate * 4;
  float* Ip = (float*)so; so += nstate * 4;

  dim3 blk(256);
  dim3 blk8(512);
  const int wkv_grid = (int)(nstate / 4 / 256);   // 512

  mix3_castw_kernel<<<MIXGRID + CASTGRID, blk, 0, stream>>>(
      x, tmk, tmv, tmr, xkb, xvb, xrb,
      Wk, Wv, Wr, Wo, Wkb, Wvb, Wrb, Wob);
  gemm8_kvr<<<768, blk8, 0, stream>>>(xkb, xvb, xrb, Wkb, Wvb, Wrb,
                                      kbuf, vbuf, rbuf);

  wkv_phase1<<<wkv_grid, blk, 0, stream>>>(kbuf, vbuf, tdec, Sa, Sb, Sp);
  wkv_phase2<<<(BB * CC + 255) / 256, blk, 0, stream>>>(tdec, Sa, Sb, Sp, Ia, Ib, Ip);
  wkv_phase3<<<wkv_grid, blk, 0, stream>>>(kbuf, vbuf, rbuf, tdec, tfir,
                                           Ia, Ib, Ip, rbuf);  // in-place gate

  gemm8_one<<<256, blk8, 0, stream>>>(rbuf, Wob, (float*)d_out);
}